// Round 3
// baseline (1886.403 us; speedup 1.0000x reference)
//
#include <hip/hip_runtime.h>
#include <hip/hip_bf16.h>
#include <cstdint>
#include <cstddef>

#define L_TOK 577
#define DM 256
#define DI 512
#define DS_ 64
#define NROWS (16*577)      // 9232
#define PROWS (16*576)      // 9216

typedef float f32x4v __attribute__((ext_vector_type(4)));
typedef __bf16 bf16x8 __attribute__((ext_vector_type(8)));

__device__ __forceinline__ float fast_exp2(float x) {
#if __has_builtin(__builtin_amdgcn_exp2f)
    return __builtin_amdgcn_exp2f(x);
#else
    return __expf(x * 0.6931471805599453f);
#endif
}

// ---------------- GEMM: C[M,N] = A[M,K] * B[N,K]^T  (+C if beta) -------------
__global__ __launch_bounds__(256)
void k_gemm(const float* __restrict__ A, int lda,
            const float* __restrict__ B, int ldb,
            float* __restrict__ C, int ldc,
            int M, int N, int K, int beta)
{
    __shared__ char sA[128*64*2];
    __shared__ char sB[128*64*2];
    const int tid  = threadIdx.x;
    const int lane = tid & 63;
    const int wave = tid >> 6;
    const int wr = wave >> 1, wc = wave & 1;
    const int tm = blockIdx.y * 128, tn = blockIdx.x * 128;

    f32x4v acc[4][4];
#pragma unroll
    for (int m = 0; m < 4; ++m)
#pragma unroll
        for (int n = 0; n < 4; ++n) acc[m][n] = (f32x4v){0.f, 0.f, 0.f, 0.f};

    const int nk = K >> 6;
    for (int kt = 0; kt < nk; ++kt) {
        const int k0 = kt << 6;
        __syncthreads();
#pragma unroll
        for (int i = 0; i < 4; ++i) {
            int c = tid + (i << 8);
            int row = c >> 3, slot = c & 7;
            int gr = tm + row; gr = gr < M ? gr : M - 1;
            const float* src = A + (size_t)gr * lda + k0 + (slot << 3);
            float4 lo = *reinterpret_cast<const float4*>(src);
            float4 hi = *reinterpret_cast<const float4*>(src + 4);
            bf16x8 pk;
            pk[0]=(__bf16)lo.x; pk[1]=(__bf16)lo.y; pk[2]=(__bf16)lo.z; pk[3]=(__bf16)lo.w;
            pk[4]=(__bf16)hi.x; pk[5]=(__bf16)hi.y; pk[6]=(__bf16)hi.z; pk[7]=(__bf16)hi.w;
            *reinterpret_cast<bf16x8*>(&sA[(row << 7) + ((slot ^ (row & 7)) << 4)]) = pk;
        }
#pragma unroll
        for (int i = 0; i < 4; ++i) {
            int c = tid + (i << 8);
            int row = c >> 3, slot = c & 7;
            int gr = tn + row; gr = gr < N ? gr : N - 1;
            const float* src = B + (size_t)gr * ldb + k0 + (slot << 3);
            float4 lo = *reinterpret_cast<const float4*>(src);
            float4 hi = *reinterpret_cast<const float4*>(src + 4);
            bf16x8 pk;
            pk[0]=(__bf16)lo.x; pk[1]=(__bf16)lo.y; pk[2]=(__bf16)lo.z; pk[3]=(__bf16)lo.w;
            pk[4]=(__bf16)hi.x; pk[5]=(__bf16)hi.y; pk[6]=(__bf16)hi.z; pk[7]=(__bf16)hi.w;
            *reinterpret_cast<bf16x8*>(&sB[(row << 7) + ((slot ^ (row & 7)) << 4)]) = pk;
        }
        __syncthreads();

        bf16x8 af[4][2], bfr[4][2];
#pragma unroll
        for (int kk = 0; kk < 2; ++kk) {
            int sl = (kk << 2) + (lane >> 4);
#pragma unroll
            for (int m = 0; m < 4; ++m) {
                int row = (wr << 6) + (m << 4) + (lane & 15);
                af[m][kk] = *reinterpret_cast<const bf16x8*>(&sA[(row << 7) + ((sl ^ (row & 7)) << 4)]);
            }
#pragma unroll
            for (int n = 0; n < 4; ++n) {
                int row = (wc << 6) + (n << 4) + (lane & 15);
                bfr[n][kk] = *reinterpret_cast<const bf16x8*>(&sB[(row << 7) + ((sl ^ (row & 7)) << 4)]);
            }
        }
#pragma unroll
        for (int kk = 0; kk < 2; ++kk)
#pragma unroll
            for (int m = 0; m < 4; ++m)
#pragma unroll
                for (int n = 0; n < 4; ++n)
                    acc[m][n] = __builtin_amdgcn_mfma_f32_16x16x32_bf16(af[m][kk], bfr[n][kk], acc[m][n], 0, 0, 0);
    }

#pragma unroll
    for (int m = 0; m < 4; ++m) {
        int grow0 = tm + (wr << 6) + (m << 4) + ((lane >> 4) << 2);
#pragma unroll
        for (int n = 0; n < 4; ++n) {
            int gcol = tn + (wc << 6) + (n << 4) + (lane & 15);
            if (gcol < N) {
#pragma unroll
                for (int j = 0; j < 4; ++j) {
                    int grow = grow0 + j;
                    if (grow < M) {
                        size_t o = (size_t)grow * ldc + gcol;
                        float v = acc[m][n][j];
                        if (beta) v += C[o];
                        C[o] = v;
                    }
                }
            }
        }
    }
}

// ---------------- im2col for patch embed: xcol[9216][768] -------------------
__global__ __launch_bounds__(256)
void k_im2col(const float* __restrict__ x, float* __restrict__ xcol)
{
    int id = blockIdx.x * 256 + threadIdx.x;
    int kh = id & 15;
    int ci = (id >> 4) % 3;
    int row = id / 48;
    int b = row / 576, p = row % 576;
    int py = p / 24, px = p % 24;
    const float* src = x + ((size_t)(b*3 + ci)*384 + py*16 + kh)*384 + px*16;
    float* dst = xcol + (size_t)row*768 + ci*256 + kh*16;
#pragma unroll
    for (int j = 0; j < 4; ++j)
        *reinterpret_cast<float4*>(dst + j*4) = *reinterpret_cast<const float4*>(src + j*4);
}

// --------- assemble tokens: cls+pos / patch+bias+pos -> h_tok ----------------
__global__ __launch_bounds__(256)
void k_assemble(const float* __restrict__ Ctmp, const float* __restrict__ pb,
                const float* __restrict__ cls, const float* __restrict__ pos,
                float* __restrict__ h_tok)
{
    int i4 = blockIdx.x * 256 + threadIdx.x;
    int c4 = i4 & 63;
    int tok = (i4 >> 6) % 577;
    int b = i4 / (577*64);
    float4 pv = *reinterpret_cast<const float4*>(pos + tok*256 + c4*4);
    float4 r;
    if (tok == 0) {
        float4 cv = *reinterpret_cast<const float4*>(cls + c4*4);
        r.x = cv.x + pv.x; r.y = cv.y + pv.y; r.z = cv.z + pv.z; r.w = cv.w + pv.w;
    } else {
        float4 t = *reinterpret_cast<const float4*>(Ctmp + (size_t)(b*576 + tok - 1)*256 + c4*4);
        float4 bb = *reinterpret_cast<const float4*>(pb + c4*4);
        r.x = t.x + bb.x + pv.x; r.y = t.y + bb.y + pv.y;
        r.z = t.z + bb.z + pv.z; r.w = t.w + bb.w + pv.w;
    }
    *reinterpret_cast<float4*>(h_tok + (size_t)i4*4) = r;
}

// ---------------- LayerNorm over 256, one wave per row ----------------------
__global__ __launch_bounds__(256)
void k_ln(const float* __restrict__ X, const float* __restrict__ w,
          const float* __restrict__ bb, float* __restrict__ O)
{
    int lane = threadIdx.x & 63;
    int row = blockIdx.x * 4 + (threadIdx.x >> 6);
    const float4 v = *reinterpret_cast<const float4*>(X + (size_t)row*256 + lane*4);
    float s1 = v.x + v.y + v.z + v.w;
    float s2 = v.x*v.x + v.y*v.y + v.z*v.z + v.w*v.w;
#pragma unroll
    for (int o2 = 32; o2; o2 >>= 1) { s1 += __shfl_xor(s1, o2); s2 += __shfl_xor(s2, o2); }
    float mu = s1 * (1.f/256.f);
    float var = s2 * (1.f/256.f) - mu*mu;
    float rs = rsqrtf(var + 1e-5f);
    float4 wv = *reinterpret_cast<const float4*>(w + lane*4);
    float4 bv = *reinterpret_cast<const float4*>(bb + lane*4);
    float4 o;
    o.x = (v.x - mu)*rs*wv.x + bv.x;
    o.y = (v.y - mu)*rs*wv.y + bv.y;
    o.z = (v.z - mu)*rs*wv.z + bv.z;
    o.w = (v.w - mu)*rs*wv.w + bv.w;
    *reinterpret_cast<float4*>(O + (size_t)row*256 + lane*4) = o;
}

// ------------- causal depthwise conv K=4 + SiLU: xz[:, :512] -> xi ----------
__global__ __launch_bounds__(256)
void k_conv(const float* __restrict__ xz, const float* __restrict__ cw,
            const float* __restrict__ cb, float* __restrict__ xi)
{
    int gw = blockIdx.x * 4 + (threadIdx.x >> 6);
    int lane = threadIdx.x & 63;
    int tc = gw % 73;
    int eg = (gw / 73) & 7;
    int b  = gw / (73*8);
    int e = eg*64 + lane;
    float4 wv = *reinterpret_cast<const float4*>(cw + e*4);
    float bias = cb[e];
    int t0 = tc * 8;
    float xv[11];
#pragma unroll
    for (int j = 0; j < 11; ++j) {
        int t = t0 - 3 + j;
        xv[j] = (t >= 0 && t < 577) ? xz[(size_t)(b*577 + t)*1024 + e] : 0.f;
    }
#pragma unroll
    for (int j = 0; j < 8; ++j) {
        int t = t0 + j;
        if (t < 577) {
            float a = wv.x*xv[j] + wv.y*xv[j+1] + wv.z*xv[j+2] + wv.w*xv[j+3] + bias;
            float sgm = 1.f / (1.f + __expf(-a));
            xi[(size_t)(b*577 + t)*512 + e] = a * sgm;
        }
    }
}

// ---- dt_proj (K=16) + softplus; writes tri2[row][d] = {dt, dt*u} -----------
__global__ __launch_bounds__(256)
void k_dtfuse(const float* __restrict__ dbl, const float* __restrict__ dtw,
              const float* __restrict__ dtb, const float* __restrict__ xi,
              float* __restrict__ tri2)
{
    int row = blockIdx.x >> 1;
    int e = ((blockIdx.x & 1) << 8) + threadIdx.x;
    const float* dr = dbl + (size_t)row*144;
    const float* wp = dtw + e*16;
    float accv = dtb[e];
#pragma unroll
    for (int r = 0; r < 16; r += 4) {
        float4 wv = *reinterpret_cast<const float4*>(wp + r);
        accv += wv.x*dr[r] + wv.y*dr[r+1] + wv.z*dr[r+2] + wv.w*dr[r+3];
    }
    float sp = accv > 20.f ? accv : log1pf(__expf(accv));
    float u = xi[(size_t)row*512 + e];
    float2 o; o.x = sp; o.y = sp * u;
    *reinterpret_cast<float2*>(tri2 + ((size_t)row*512 + e)*2) = o;
}

// ------------- selective scan: wave = (b, d), lane = state s ----------------
// Chunked (T=16): B/C staged once per 4-wave block in LDS (L2 traffic /4);
// per-step p kept in regs; transpose-reduce via per-wave LDS pad (stride 65,
// conflict-free) + 2 shfl_xor. tri2 via wave-uniform s_load. u*D in k_gate.
__global__ __launch_bounds__(256, 6)
void k_scan(const float* __restrict__ tri2, const float* __restrict__ dbl,
            const float* __restrict__ A_log, float* __restrict__ y)
{
    __shared__ float bc[16*128];     // 8 KB: [t][B(64)|C(64)] panel
    __shared__ float tp[4*16*65];    // 16.25 KB: per-wave transpose pad
    const int tid  = threadIdx.x;
    const int lane = tid & 63;
    const int wv   = tid >> 6;                                            // 0..3
    const int bb   = blockIdx.x >> 7;                                     // batch
    const int d    = __builtin_amdgcn_readfirstlane(((blockIdx.x & 127) << 2) + wv);
    const float alog2 = -__expf(A_log[(size_t)d*64 + lane]) * 1.44269504f;
    const size_t row0 = (size_t)bb * 577;
    const float2* trip = reinterpret_cast<const float2*>(tri2) + row0*512 + d;  // uniform
    const float* dblb = dbl + row0*144 + 16;
    float* yp = y + row0*512 + d;
    float* tpw = tp + wv*(16*65);
    const int j0 = tid >> 5, q = tid & 31;   // staging: rows j0, j0+8; 32 f4/row
    float h = 0.f;

    for (int c = 0; c < 36; ++c) {
        const int t0 = c << 4;
        __syncthreads();
        {   // stage B|C rows t0..t0+15 (coalesced 512B/row)
            const float* s0 = dblb + (size_t)(t0 + j0)*144 + q*4;
            const float* s1 = dblb + (size_t)(t0 + j0 + 8)*144 + q*4;
            float4 v0 = *reinterpret_cast<const float4*>(s0);
            float4 v1 = *reinterpret_cast<const float4*>(s1);
            *reinterpret_cast<float4*>(&bc[j0*128 + q*4]) = v0;
            *reinterpret_cast<float4*>(&bc[(j0+8)*128 + q*4]) = v1;
        }
        __syncthreads();
        float p[16];
#pragma unroll
        for (int j = 0; j < 16; ++j) {
            float2 tr = trip[(size_t)(t0 + j)*512];   // s_load_dwordx2
            float Bv = bc[j*128 + lane];
            float Cv = bc[j*128 + 64 + lane];
            float dA = fast_exp2(tr.x * alog2);
            h = __builtin_fmaf(dA, h, tr.y * Bv);
            p[j] = h * Cv;
        }
        // transpose-reduce: lane (g,t') sums s-range [16g,16g+16) of row t'
#pragma unroll
        for (int j = 0; j < 16; ++j) tpw[j*65 + lane] = p[j];
        float partial = 0.f;
        {
            const int g = lane >> 4, tt = lane & 15;
            const float* rp = tpw + tt*65 + g*16;
#pragma unroll
            for (int k = 0; k < 16; ++k) partial += rp[k];
        }
        partial += __shfl_xor(partial, 16);
        partial += __shfl_xor(partial, 32);
        if (lane < 16) yp[(size_t)(t0 + lane)*512] = partial;
    }
    {   // tail t = 576
        float2 tr = trip[(size_t)576*512];
        float Bv = dblb[(size_t)576*144 + lane];
        float Cv = dblb[(size_t)576*144 + 64 + lane];
        float dA = fast_exp2(tr.x * alog2);
        h = __builtin_fmaf(dA, h, tr.y * Bv);
        float p = h * Cv;
        p += __shfl_xor(p, 32); p += __shfl_xor(p, 16); p += __shfl_xor(p, 8);
        p += __shfl_xor(p, 4);  p += __shfl_xor(p, 2);  p += __shfl_xor(p, 1);
        if (lane == 0) yp[(size_t)576*512] = p;
    }
}

// ------------- y = (y + u*D) * silu(z)  (in place on y) ---------------------
__global__ __launch_bounds__(256)
void k_gate(float* __restrict__ y, const float* __restrict__ xz,
            const float* __restrict__ xi, const float* __restrict__ Dp)
{
    int i4 = blockIdx.x * 256 + threadIdx.x;   // 9232*128 f4
    int row = i4 >> 7;
    int c4 = i4 & 127;
    float4 yv = *reinterpret_cast<float4*>(y + (size_t)i4*4);
    float4 uv = *reinterpret_cast<const float4*>(xi + (size_t)i4*4);
    float4 dv = *reinterpret_cast<const float4*>(Dp + c4*4);
    const float4 zv = *reinterpret_cast<const float4*>(xz + (size_t)row*1024 + 512 + c4*4);
    float4 o;
    o.x = (yv.x + uv.x*dv.x) * (zv.x / (1.f + __expf(-zv.x)));
    o.y = (yv.y + uv.y*dv.y) * (zv.y / (1.f + __expf(-zv.y)));
    o.z = (yv.z + uv.z*dv.z) * (zv.z / (1.f + __expf(-zv.z)));
    o.w = (yv.w + uv.w*dv.w) * (zv.w / (1.f + __expf(-zv.w)));
    *reinterpret_cast<float4*>(y + (size_t)i4*4) = o;
}

// ---------------- final LN (cls token) + head -------------------------------
__global__ __launch_bounds__(256)
void k_head(const float* __restrict__ h_tok, const float* __restrict__ fw,
            const float* __restrict__ fb, const float* __restrict__ hw,
            const float* __restrict__ hb, float* __restrict__ out)
{
    int b = blockIdx.x, tid = threadIdx.x;
    __shared__ float sv[256];
    __shared__ float sr[16];
    float v = h_tok[(size_t)b*577*256 + tid];
    float s1 = v, s2 = v*v;
#pragma unroll
    for (int o2 = 32; o2; o2 >>= 1) { s1 += __shfl_xor(s1, o2); s2 += __shfl_xor(s2, o2); }
    int wave = tid >> 6;
    if ((tid & 63) == 0) { sr[wave] = s1; sr[wave + 8] = s2; }
    __syncthreads();
    float t1 = sr[0] + sr[1] + sr[2] + sr[3];
    float t2 = sr[8] + sr[9] + sr[10] + sr[11];
    float mu = t1 * (1.f/256.f);
    float var = t2 * (1.f/256.f) - mu*mu;
    float rs = rsqrtf(var + 1e-5f);
    sv[tid] = (v - mu)*rs*fw[tid] + fb[tid];
    __syncthreads();
    if (tid < 10) {
        float acc = hb[tid];
        for (int d2 = 0; d2 < 256; ++d2) acc += sv[d2]*hw[tid*256 + d2];
        out[b*10 + tid] = acc;
    }
}

extern "C" void kernel_launch(void* const* d_in, const int* in_sizes, int n_in,
                              void* d_out, int out_size, void* d_ws, size_t ws_size,
                              hipStream_t stream)
{
    const float* x         = (const float*)d_in[0];
    const float* patch_w   = (const float*)d_in[1];
    const float* patch_b   = (const float*)d_in[2];
    const float* cls_tok   = (const float*)d_in[3];
    const float* pos_emb   = (const float*)d_in[4];
    const float* norm_w    = (const float*)d_in[5];
    const float* norm_b    = (const float*)d_in[6];
    const float* in_proj_w = (const float*)d_in[7];
    const float* conv_w    = (const float*)d_in[8];
    const float* conv_b    = (const float*)d_in[9];
    const float* x_proj_w  = (const float*)d_in[10];
    const float* dt_proj_w = (const float*)d_in[11];
    const float* dt_proj_b = (const float*)d_in[12];
    const float* A_log     = (const float*)d_in[13];
    const float* D_ssm     = (const float*)d_in[14];
    const float* out_proj_w= (const float*)d_in[15];
    const float* fnorm_w   = (const float*)d_in[16];
    const float* fnorm_b   = (const float*)d_in[17];
    const float* head_w    = (const float*)d_in[18];
    const float* head_b    = (const float*)d_in[19];
    float* out = (float*)d_out;

    char* ws = (char*)d_ws;
    size_t off = 0;
    auto carve = [&](size_t bytes) -> float* {
        float* p = (float*)(ws + off);
        off += (bytes + 255) & ~(size_t)255;
        return p;
    };
    float* h_tok = carve((size_t)NROWS*DM*4);       //  9.45 MB
    float* xln   = carve((size_t)NROWS*DM*4);       //  9.45 MB
    float* xz    = carve((size_t)NROWS*1024*4);     // 37.8 MB (alias: xcol)
    float* xi    = carve((size_t)NROWS*DI*4);       // 18.9 MB (alias: Ctmp)
    float* dbl   = carve((size_t)NROWS*144*4);      //  5.3 MB
    float* tri2  = carve((size_t)NROWS*DI*2*4);     // 37.8 MB
    float* yb    = carve((size_t)NROWS*DI*4);       // 18.9 MB
    float* xcol  = xz;
    float* Ctmp  = xi;

    // ---- patch embed ----
    k_im2col<<<1728, 256, 0, stream>>>(x, xcol);
    {
        dim3 g(2, 72);
        k_gemm<<<g, 256, 0, stream>>>(xcol, 768, patch_w, 768, Ctmp, 256, PROWS, 256, 768, 0);
    }
    k_assemble<<<2308, 256, 0, stream>>>(Ctmp, patch_b, cls_tok, pos_emb, h_tok);

    // ---- 6 mamba blocks ----
    for (int i = 0; i < 6; ++i) {
        k_ln<<<2308, 256, 0, stream>>>(h_tok, norm_w + i*DM, norm_b + i*DM, xln);
        {
            dim3 g(8, 73);
            k_gemm<<<g, 256, 0, stream>>>(xln, DM, in_proj_w + (size_t)i*1024*DM, DM,
                                          xz, 1024, NROWS, 1024, DM, 0);
        }
        k_conv<<<2336, 256, 0, stream>>>(xz, conv_w + (size_t)i*DI*4, conv_b + i*DI, xi);
        {
            dim3 g(2, 73);
            k_gemm<<<g, 256, 0, stream>>>(xi, DI, x_proj_w + (size_t)i*144*DI, DI,
                                          dbl, 144, NROWS, 144, DI, 0);
        }
        k_dtfuse<<<NROWS*2, 256, 0, stream>>>(dbl, dt_proj_w + (size_t)i*DI*16, dt_proj_b + i*DI,
                                              xi, tri2);
        k_scan<<<2048, 256, 0, stream>>>(tri2, dbl, A_log + (size_t)i*DI*DS_, yb);
        k_gate<<<4616, 256, 0, stream>>>(yb, xz, xi, D_ssm + i*DI);
        {
            dim3 g(2, 73);
            k_gemm<<<g, 256, 0, stream>>>(yb, DI, out_proj_w + (size_t)i*DM*DI, DI,
                                          h_tok, DM, NROWS, DM, DI, 1);
        }
    }
    k_head<<<16, 256, 0, stream>>>(h_tok, fnorm_w, fnorm_b, head_w, head_b, out);
}

// Round 4
// 1845.806 us; speedup vs baseline: 1.0220x; 1.0220x over previous
//
#include <hip/hip_runtime.h>
#include <hip/hip_bf16.h>
#include <cstdint>
#include <cstddef>

#define L_TOK 577
#define DM 256
#define DI 512
#define DS_ 64
#define NROWS (16*577)      // 9232
#define PROWS (16*576)      // 9216
#define NCH 37              // ceil(577/16) time chunks

typedef float f32x4v __attribute__((ext_vector_type(4)));
typedef __bf16 bf16x8 __attribute__((ext_vector_type(8)));

__device__ __forceinline__ float fast_exp2(float x) {
#if __has_builtin(__builtin_amdgcn_exp2f)
    return __builtin_amdgcn_exp2f(x);
#else
    return __expf(x * 0.6931471805599453f);
#endif
}

// ---------------- GEMM: C[M,N] = A[M,K] * B[N,K]^T  (+C if beta) -------------
__global__ __launch_bounds__(256)
void k_gemm(const float* __restrict__ A, int lda,
            const float* __restrict__ B, int ldb,
            float* __restrict__ C, int ldc,
            int M, int N, int K, int beta)
{
    __shared__ char sA[128*64*2];
    __shared__ char sB[128*64*2];
    const int tid  = threadIdx.x;
    const int lane = tid & 63;
    const int wave = tid >> 6;
    const int wr = wave >> 1, wc = wave & 1;
    const int tm = blockIdx.y * 128, tn = blockIdx.x * 128;

    f32x4v acc[4][4];
#pragma unroll
    for (int m = 0; m < 4; ++m)
#pragma unroll
        for (int n = 0; n < 4; ++n) acc[m][n] = (f32x4v){0.f, 0.f, 0.f, 0.f};

    const int nk = K >> 6;
    for (int kt = 0; kt < nk; ++kt) {
        const int k0 = kt << 6;
        __syncthreads();
#pragma unroll
        for (int i = 0; i < 4; ++i) {
            int c = tid + (i << 8);
            int row = c >> 3, slot = c & 7;
            int gr = tm + row; gr = gr < M ? gr : M - 1;
            const float* src = A + (size_t)gr * lda + k0 + (slot << 3);
            float4 lo = *reinterpret_cast<const float4*>(src);
            float4 hi = *reinterpret_cast<const float4*>(src + 4);
            bf16x8 pk;
            pk[0]=(__bf16)lo.x; pk[1]=(__bf16)lo.y; pk[2]=(__bf16)lo.z; pk[3]=(__bf16)lo.w;
            pk[4]=(__bf16)hi.x; pk[5]=(__bf16)hi.y; pk[6]=(__bf16)hi.z; pk[7]=(__bf16)hi.w;
            *reinterpret_cast<bf16x8*>(&sA[(row << 7) + ((slot ^ (row & 7)) << 4)]) = pk;
        }
#pragma unroll
        for (int i = 0; i < 4; ++i) {
            int c = tid + (i << 8);
            int row = c >> 3, slot = c & 7;
            int gr = tn + row; gr = gr < N ? gr : N - 1;
            const float* src = B + (size_t)gr * ldb + k0 + (slot << 3);
            float4 lo = *reinterpret_cast<const float4*>(src);
            float4 hi = *reinterpret_cast<const float4*>(src + 4);
            bf16x8 pk;
            pk[0]=(__bf16)lo.x; pk[1]=(__bf16)lo.y; pk[2]=(__bf16)lo.z; pk[3]=(__bf16)lo.w;
            pk[4]=(__bf16)hi.x; pk[5]=(__bf16)hi.y; pk[6]=(__bf16)hi.z; pk[7]=(__bf16)hi.w;
            *reinterpret_cast<bf16x8*>(&sB[(row << 7) + ((slot ^ (row & 7)) << 4)]) = pk;
        }
        __syncthreads();

        bf16x8 af[4][2], bfr[4][2];
#pragma unroll
        for (int kk = 0; kk < 2; ++kk) {
            int sl = (kk << 2) + (lane >> 4);
#pragma unroll
            for (int m = 0; m < 4; ++m) {
                int row = (wr << 6) + (m << 4) + (lane & 15);
                af[m][kk] = *reinterpret_cast<const bf16x8*>(&sA[(row << 7) + ((sl ^ (row & 7)) << 4)]);
            }
#pragma unroll
            for (int n = 0; n < 4; ++n) {
                int row = (wc << 6) + (n << 4) + (lane & 15);
                bfr[n][kk] = *reinterpret_cast<const bf16x8*>(&sB[(row << 7) + ((sl ^ (row & 7)) << 4)]);
            }
        }
#pragma unroll
        for (int kk = 0; kk < 2; ++kk)
#pragma unroll
            for (int m = 0; m < 4; ++m)
#pragma unroll
                for (int n = 0; n < 4; ++n)
                    acc[m][n] = __builtin_amdgcn_mfma_f32_16x16x32_bf16(af[m][kk], bfr[n][kk], acc[m][n], 0, 0, 0);
    }

#pragma unroll
    for (int m = 0; m < 4; ++m) {
        int grow0 = tm + (wr << 6) + (m << 4) + ((lane >> 4) << 2);
#pragma unroll
        for (int n = 0; n < 4; ++n) {
            int gcol = tn + (wc << 6) + (n << 4) + (lane & 15);
            if (gcol < N) {
#pragma unroll
                for (int j = 0; j < 4; ++j) {
                    int grow = grow0 + j;
                    if (grow < M) {
                        size_t o = (size_t)grow * ldc + gcol;
                        float v = acc[m][n][j];
                        if (beta) v += C[o];
                        C[o] = v;
                    }
                }
            }
        }
    }
}

// ---------------- im2col for patch embed: xcol[9216][768] -------------------
__global__ __launch_bounds__(256)
void k_im2col(const float* __restrict__ x, float* __restrict__ xcol)
{
    int id = blockIdx.x * 256 + threadIdx.x;
    int kh = id & 15;
    int ci = (id >> 4) % 3;
    int row = id / 48;
    int b = row / 576, p = row % 576;
    int py = p / 24, px = p % 24;
    const float* src = x + ((size_t)(b*3 + ci)*384 + py*16 + kh)*384 + px*16;
    float* dst = xcol + (size_t)row*768 + ci*256 + kh*16;
#pragma unroll
    for (int j = 0; j < 4; ++j)
        *reinterpret_cast<float4*>(dst + j*4) = *reinterpret_cast<const float4*>(src + j*4);
}

// --------- assemble tokens: cls+pos / patch+bias+pos -> h_tok ----------------
__global__ __launch_bounds__(256)
void k_assemble(const float* __restrict__ Ctmp, const float* __restrict__ pb,
                const float* __restrict__ cls, const float* __restrict__ pos,
                float* __restrict__ h_tok)
{
    int i4 = blockIdx.x * 256 + threadIdx.x;
    int c4 = i4 & 63;
    int tok = (i4 >> 6) % 577;
    int b = i4 / (577*64);
    float4 pv = *reinterpret_cast<const float4*>(pos + tok*256 + c4*4);
    float4 r;
    if (tok == 0) {
        float4 cv = *reinterpret_cast<const float4*>(cls + c4*4);
        r.x = cv.x + pv.x; r.y = cv.y + pv.y; r.z = cv.z + pv.z; r.w = cv.w + pv.w;
    } else {
        float4 t = *reinterpret_cast<const float4*>(Ctmp + (size_t)(b*576 + tok - 1)*256 + c4*4);
        float4 bb = *reinterpret_cast<const float4*>(pb + c4*4);
        r.x = t.x + bb.x + pv.x; r.y = t.y + bb.y + pv.y;
        r.z = t.z + bb.z + pv.z; r.w = t.w + bb.w + pv.w;
    }
    *reinterpret_cast<float4*>(h_tok + (size_t)i4*4) = r;
}

// ---------------- LayerNorm over 256, one wave per row ----------------------
__global__ __launch_bounds__(256)
void k_ln(const float* __restrict__ X, const float* __restrict__ w,
          const float* __restrict__ bb, float* __restrict__ O)
{
    int lane = threadIdx.x & 63;
    int row = blockIdx.x * 4 + (threadIdx.x >> 6);
    const float4 v = *reinterpret_cast<const float4*>(X + (size_t)row*256 + lane*4);
    float s1 = v.x + v.y + v.z + v.w;
    float s2 = v.x*v.x + v.y*v.y + v.z*v.z + v.w*v.w;
#pragma unroll
    for (int o2 = 32; o2; o2 >>= 1) { s1 += __shfl_xor(s1, o2); s2 += __shfl_xor(s2, o2); }
    float mu = s1 * (1.f/256.f);
    float var = s2 * (1.f/256.f) - mu*mu;
    float rs = rsqrtf(var + 1e-5f);
    float4 wv = *reinterpret_cast<const float4*>(w + lane*4);
    float4 bv = *reinterpret_cast<const float4*>(bb + lane*4);
    float4 o;
    o.x = (v.x - mu)*rs*wv.x + bv.x;
    o.y = (v.y - mu)*rs*wv.y + bv.y;
    o.z = (v.z - mu)*rs*wv.z + bv.z;
    o.w = (v.w - mu)*rs*wv.w + bv.w;
    *reinterpret_cast<float4*>(O + (size_t)row*256 + lane*4) = o;
}

// ------------- causal depthwise conv K=4 + SiLU: xz[:, :512] -> xi ----------
__global__ __launch_bounds__(256)
void k_conv(const float* __restrict__ xz, const float* __restrict__ cw,
            const float* __restrict__ cb, float* __restrict__ xi)
{
    int gw = blockIdx.x * 4 + (threadIdx.x >> 6);
    int lane = threadIdx.x & 63;
    int tc = gw % 73;
    int eg = (gw / 73) & 7;
    int b  = gw / (73*8);
    int e = eg*64 + lane;
    float4 wv = *reinterpret_cast<const float4*>(cw + e*4);
    float bias = cb[e];
    int t0 = tc * 8;
    float xv[11];
#pragma unroll
    for (int j = 0; j < 11; ++j) {
        int t = t0 - 3 + j;
        xv[j] = (t >= 0 && t < 577) ? xz[(size_t)(b*577 + t)*1024 + e] : 0.f;
    }
#pragma unroll
    for (int j = 0; j < 8; ++j) {
        int t = t0 + j;
        if (t < 577) {
            float a = wv.x*xv[j] + wv.y*xv[j+1] + wv.z*xv[j+2] + wv.w*xv[j+3] + bias;
            float sgm = 1.f / (1.f + __expf(-a));
            xi[(size_t)(b*577 + t)*512 + e] = a * sgm;
        }
    }
}

// ---- dt_proj (K=16) + softplus; writes tri2c[b][tc][e][j] = {dt, dt*u} ------
// chunk-contiguous layout: ((b*37 + tc)*512 + e)*32 + j*2
__global__ __launch_bounds__(256)
void k_dtfuse(const float* __restrict__ dbl, const float* __restrict__ dtw,
              const float* __restrict__ dtb, const float* __restrict__ xi,
              float* __restrict__ tri2)
{
    __shared__ float dtr[16][16];
    const int tid = threadIdx.x;
    const int b    = blockIdx.x / 74;
    const int rr   = blockIdx.x % 74;
    const int tc   = rr >> 1;
    const int e    = ((rr & 1) << 8) + tid;
    const int nj   = (tc == 36) ? 1 : 16;
    {   // stage dt-rank rows for this chunk
        int j = tid >> 4, r = tid & 15;
        if (tid < 256 && j < nj)
            dtr[j][r] = dbl[((size_t)(b*577) + tc*16 + j)*144 + r];
    }
    __syncthreads();
    const float* wp = dtw + e*16;
    float4 w0 = *reinterpret_cast<const float4*>(wp);
    float4 w1 = *reinterpret_cast<const float4*>(wp + 4);
    float4 w2 = *reinterpret_cast<const float4*>(wp + 8);
    float4 w3 = *reinterpret_cast<const float4*>(wp + 12);
    float bias = dtb[e];
    float* outp = tri2 + ((size_t)(b*37 + tc)*512 + e)*32;
    for (int j = 0; j < nj; ++j) {
        const float* dr = dtr[j];
        float accv = bias;
        accv += w0.x*dr[0] + w0.y*dr[1] + w0.z*dr[2] + w0.w*dr[3];
        accv += w1.x*dr[4] + w1.y*dr[5] + w1.z*dr[6] + w1.w*dr[7];
        accv += w2.x*dr[8] + w2.y*dr[9] + w2.z*dr[10] + w2.w*dr[11];
        accv += w3.x*dr[12] + w3.y*dr[13] + w3.z*dr[14] + w3.w*dr[15];
        float sp = accv > 20.f ? accv : log1pf(__expf(accv));
        float u = xi[((size_t)(b*577) + tc*16 + j)*512 + e];
        float2 o; o.x = sp; o.y = sp * u;
        *reinterpret_cast<float2*>(outp + j*2) = o;
    }
}

// ------------- selective scan: wave = (b, d), lane = state s ----------------
// Per-wave chunked (T=16), NO barriers: tri2 chunk = one 128B uniform block
// (merged s_loads); B/C per-lane VMEM (L2-hot, 32 in flight); per-wave LDS
// transpose pad (stride 65, conflict-free) + 2 shfl. u*D applied in k_gate.
__global__ __launch_bounds__(256, 6)
void k_scan(const float* __restrict__ tri2, const float* __restrict__ dbl,
            const float* __restrict__ A_log, float* __restrict__ y)
{
    __shared__ float tp[4*16*65];    // 16.25 KB, per-wave private regions
    const int tid  = threadIdx.x;
    const int lane = tid & 63;
    const int wv   = tid >> 6;                                            // 0..3
    const int bb   = blockIdx.x >> 7;                                     // batch
    const int d    = __builtin_amdgcn_readfirstlane(((blockIdx.x & 127) << 2) + wv);
    const float alog2 = -__expf(A_log[(size_t)d*64 + lane]) * 1.44269504f;
    const float2* trp = reinterpret_cast<const float2*>(tri2)
                      + ((size_t)bb*NCH*512 + d)*16;                      // uniform
    const float* Bb = dbl + (size_t)bb*577*144 + 16 + lane;
    float* yp = y + (size_t)bb*577*512 + d;
    float* tpw = tp + wv*(16*65);
    const int g = lane >> 4, tt = lane & 15;
    float h = 0.f;

    for (int c = 0; c < 36; ++c) {
        const int t0 = c << 4;
        float p[16];
#pragma unroll
        for (int j = 0; j < 16; ++j) {
            float2 tr = trp[(size_t)c*8192 + j];      // merged s_load_dwordxN
            float Bv = Bb[(size_t)(t0 + j)*144];
            float Cv = Bb[(size_t)(t0 + j)*144 + 64];
            float dA = fast_exp2(tr.x * alog2);
            h = __builtin_fmaf(dA, h, tr.y * Bv);
            p[j] = h * Cv;
        }
#pragma unroll
        for (int j = 0; j < 16; ++j) tpw[j*65 + lane] = p[j];
        float partial = 0.f;
        {
            const float* rp = tpw + tt*65 + g*16;
#pragma unroll
            for (int k = 0; k < 16; ++k) partial += rp[k];
        }
        partial += __shfl_xor(partial, 16);
        partial += __shfl_xor(partial, 32);
        if (lane < 16) yp[(size_t)(t0 + tt)*512] = partial;
    }
    {   // tail t = 576 (chunk 36, j = 0)
        float2 tr = trp[(size_t)36*8192];
        float Bv = Bb[(size_t)576*144];
        float Cv = Bb[(size_t)576*144 + 64];
        float dA = fast_exp2(tr.x * alog2);
        h = __builtin_fmaf(dA, h, tr.y * Bv);
        float p = h * Cv;
        p += __shfl_xor(p, 32); p += __shfl_xor(p, 16); p += __shfl_xor(p, 8);
        p += __shfl_xor(p, 4);  p += __shfl_xor(p, 2);  p += __shfl_xor(p, 1);
        if (lane == 0) yp[(size_t)576*512] = p;
    }
}

// ------------- y = (y + u*D) * silu(z)  (in place on y) ---------------------
__global__ __launch_bounds__(256)
void k_gate(float* __restrict__ y, const float* __restrict__ xz,
            const float* __restrict__ xi, const float* __restrict__ Dp)
{
    int i4 = blockIdx.x * 256 + threadIdx.x;   // 9232*128 f4
    int row = i4 >> 7;
    int c4 = i4 & 127;
    float4 yv = *reinterpret_cast<float4*>(y + (size_t)i4*4);
    float4 uv = *reinterpret_cast<const float4*>(xi + (size_t)i4*4);
    float4 dv = *reinterpret_cast<const float4*>(Dp + c4*4);
    const float4 zv = *reinterpret_cast<const float4*>(xz + (size_t)row*1024 + 512 + c4*4);
    float4 o;
    o.x = (yv.x + uv.x*dv.x) * (zv.x / (1.f + __expf(-zv.x)));
    o.y = (yv.y + uv.y*dv.y) * (zv.y / (1.f + __expf(-zv.y)));
    o.z = (yv.z + uv.z*dv.z) * (zv.z / (1.f + __expf(-zv.z)));
    o.w = (yv.w + uv.w*dv.w) * (zv.w / (1.f + __expf(-zv.w)));
    *reinterpret_cast<float4*>(y + (size_t)i4*4) = o;
}

// ---------------- final LN (cls token) + head -------------------------------
__global__ __launch_bounds__(256)
void k_head(const float* __restrict__ h_tok, const float* __restrict__ fw,
            const float* __restrict__ fb, const float* __restrict__ hw,
            const float* __restrict__ hb, float* __restrict__ out)
{
    int b = blockIdx.x, tid = threadIdx.x;
    __shared__ float sv[256];
    __shared__ float sr[16];
    float v = h_tok[(size_t)b*577*256 + tid];
    float s1 = v, s2 = v*v;
#pragma unroll
    for (int o2 = 32; o2; o2 >>= 1) { s1 += __shfl_xor(s1, o2); s2 += __shfl_xor(s2, o2); }
    int wave = tid >> 6;
    if ((tid & 63) == 0) { sr[wave] = s1; sr[wave + 8] = s2; }
    __syncthreads();
    float t1 = sr[0] + sr[1] + sr[2] + sr[3];
    float t2 = sr[8] + sr[9] + sr[10] + sr[11];
    float mu = t1 * (1.f/256.f);
    float var = t2 * (1.f/256.f) - mu*mu;
    float rs = rsqrtf(var + 1e-5f);
    sv[tid] = (v - mu)*rs*fw[tid] + fb[tid];
    __syncthreads();
    if (tid < 10) {
        float acc = hb[tid];
        for (int d2 = 0; d2 < 256; ++d2) acc += sv[d2]*hw[tid*256 + d2];
        out[b*10 + tid] = acc;
    }
}

extern "C" void kernel_launch(void* const* d_in, const int* in_sizes, int n_in,
                              void* d_out, int out_size, void* d_ws, size_t ws_size,
                              hipStream_t stream)
{
    const float* x         = (const float*)d_in[0];
    const float* patch_w   = (const float*)d_in[1];
    const float* patch_b   = (const float*)d_in[2];
    const float* cls_tok   = (const float*)d_in[3];
    const float* pos_emb   = (const float*)d_in[4];
    const float* norm_w    = (const float*)d_in[5];
    const float* norm_b    = (const float*)d_in[6];
    const float* in_proj_w = (const float*)d_in[7];
    const float* conv_w    = (const float*)d_in[8];
    const float* conv_b    = (const float*)d_in[9];
    const float* x_proj_w  = (const float*)d_in[10];
    const float* dt_proj_w = (const float*)d_in[11];
    const float* dt_proj_b = (const float*)d_in[12];
    const float* A_log     = (const float*)d_in[13];
    const float* D_ssm     = (const float*)d_in[14];
    const float* out_proj_w= (const float*)d_in[15];
    const float* fnorm_w   = (const float*)d_in[16];
    const float* fnorm_b   = (const float*)d_in[17];
    const float* head_w    = (const float*)d_in[18];
    const float* head_b    = (const float*)d_in[19];
    float* out = (float*)d_out;

    char* ws = (char*)d_ws;
    size_t off = 0;
    auto carve = [&](size_t bytes) -> float* {
        float* p = (float*)(ws + off);
        off += (bytes + 255) & ~(size_t)255;
        return p;
    };
    float* h_tok = carve((size_t)NROWS*DM*4);           //  9.45 MB
    float* xln   = carve((size_t)NROWS*DM*4);           //  9.45 MB
    float* xz    = carve((size_t)NROWS*1024*4);         // 37.8 MB (alias: xcol)
    float* xi    = carve((size_t)NROWS*DI*4);           // 18.9 MB (alias: Ctmp)
    float* dbl   = carve((size_t)NROWS*144*4);          //  5.3 MB
    float* tri2  = carve((size_t)16*NCH*DI*32*4);       // 38.8 MB (chunked)
    float* yb    = carve((size_t)NROWS*DI*4);           // 18.9 MB
    float* xcol  = xz;
    float* Ctmp  = xi;

    // ---- patch embed ----
    k_im2col<<<1728, 256, 0, stream>>>(x, xcol);
    {
        dim3 g(2, 72);
        k_gemm<<<g, 256, 0, stream>>>(xcol, 768, patch_w, 768, Ctmp, 256, PROWS, 256, 768, 0);
    }
    k_assemble<<<2308, 256, 0, stream>>>(Ctmp, patch_b, cls_tok, pos_emb, h_tok);

    // ---- 6 mamba blocks ----
    for (int i = 0; i < 6; ++i) {
        k_ln<<<2308, 256, 0, stream>>>(h_tok, norm_w + i*DM, norm_b + i*DM, xln);
        {
            dim3 g(8, 73);
            k_gemm<<<g, 256, 0, stream>>>(xln, DM, in_proj_w + (size_t)i*1024*DM, DM,
                                          xz, 1024, NROWS, 1024, DM, 0);
        }
        k_conv<<<2336, 256, 0, stream>>>(xz, conv_w + (size_t)i*DI*4, conv_b + i*DI, xi);
        {
            dim3 g(2, 73);
            k_gemm<<<g, 256, 0, stream>>>(xi, DI, x_proj_w + (size_t)i*144*DI, DI,
                                          dbl, 144, NROWS, 144, DI, 0);
        }
        k_dtfuse<<<16*NCH*2, 256, 0, stream>>>(dbl, dt_proj_w + (size_t)i*DI*16, dt_proj_b + i*DI,
                                               xi, tri2);
        k_scan<<<2048, 256, 0, stream>>>(tri2, dbl, A_log + (size_t)i*DI*DS_, yb);
        k_gate<<<4616, 256, 0, stream>>>(yb, xz, xi, D_ssm + i*DI);
        {
            dim3 g(2, 73);
            k_gemm<<<g, 256, 0, stream>>>(yb, DI, out_proj_w + (size_t)i*DM*DI, DI,
                                          h_tok, DM, NROWS, DM, DI, 1);
        }
    }
    k_head<<<16, 256, 0, stream>>>(h_tok, fnorm_w, fnorm_b, head_w, head_b, out);
}

// Round 5
// 1693.591 us; speedup vs baseline: 1.1138x; 1.0899x over previous
//
#include <hip/hip_runtime.h>
#include <hip/hip_bf16.h>
#include <cstdint>
#include <cstddef>

#define L_TOK 577
#define DM 256
#define DI 512
#define DS_ 64
#define NROWS (16*577)      // 9232
#define PROWS (16*576)      // 9216
#define NCH 37              // ceil(577/16) time chunks

typedef float f32x4v __attribute__((ext_vector_type(4)));
typedef __bf16 bf16x8 __attribute__((ext_vector_type(8)));
typedef __bf16 bf16x4 __attribute__((ext_vector_type(4)));

__device__ __forceinline__ float fast_exp2(float x) {
#if __has_builtin(__builtin_amdgcn_exp2f)
    return __builtin_amdgcn_exp2f(x);
#else
    return __expf(x * 0.6931471805599453f);
#endif
}

__device__ __forceinline__ bf16x4 to_bf4(float a, float b, float c, float d) {
    bf16x4 r; r[0]=(__bf16)a; r[1]=(__bf16)b; r[2]=(__bf16)c; r[3]=(__bf16)d; return r;
}

// ---------------- fp32 -> bf16 bulk convert (weights) -----------------------
__global__ __launch_bounds__(256)
void k_cvt(const float* __restrict__ s, __bf16* __restrict__ d, int n4)
{
    for (int i = blockIdx.x*256 + threadIdx.x; i < n4; i += gridDim.x*256) {
        float4 v = *reinterpret_cast<const float4*>(s + (size_t)i*4);
        *reinterpret_cast<bf16x4*>(d + (size_t)i*4) = to_bf4(v.x, v.y, v.z, v.w);
    }
}

// ---------------- GEMM: C[M,N] = A[M,K] * B[N,K]^T  (bf16 in, fp32 acc) -----
// cmode: 0 = fp32 store, 1 = fp32 accumulate (+=), 2 = bf16 store
__global__ __launch_bounds__(256)
void k_gemm(const __bf16* __restrict__ A, int lda,
            const __bf16* __restrict__ B, int ldb,
            void* __restrict__ Cvp, int ldc,
            int M, int N, int K, int cmode)
{
    __shared__ char sA[128*128];   // 128 rows x 64 bf16 (XOR-swizzled 16B slots)
    __shared__ char sB[128*128];
    const int tid  = threadIdx.x;
    const int lane = tid & 63;
    const int wave = tid >> 6;
    const int wr = wave >> 1, wc = wave & 1;
    const int tm = blockIdx.y * 128, tn = blockIdx.x * 128;

    f32x4v acc[4][4];
#pragma unroll
    for (int m = 0; m < 4; ++m)
#pragma unroll
        for (int n = 0; n < 4; ++n) acc[m][n] = (f32x4v){0.f, 0.f, 0.f, 0.f};

    const int nk = K >> 6;
    for (int kt = 0; kt < nk; ++kt) {
        const int k0 = kt << 6;
        __syncthreads();
#pragma unroll
        for (int i = 0; i < 4; ++i) {
            int c = tid + (i << 8);
            int row = c >> 3, slot = c & 7;
            int gr = tm + row; gr = gr < M ? gr : M - 1;
            bf16x8 va = *reinterpret_cast<const bf16x8*>(A + (size_t)gr*lda + k0 + (slot<<3));
            *reinterpret_cast<bf16x8*>(&sA[(row << 7) + ((slot ^ (row & 7)) << 4)]) = va;
        }
#pragma unroll
        for (int i = 0; i < 4; ++i) {
            int c = tid + (i << 8);
            int row = c >> 3, slot = c & 7;
            int gr = tn + row; gr = gr < N ? gr : N - 1;
            bf16x8 vb = *reinterpret_cast<const bf16x8*>(B + (size_t)gr*ldb + k0 + (slot<<3));
            *reinterpret_cast<bf16x8*>(&sB[(row << 7) + ((slot ^ (row & 7)) << 4)]) = vb;
        }
        __syncthreads();

        bf16x8 af[4][2], bfr[4][2];
#pragma unroll
        for (int kk = 0; kk < 2; ++kk) {
            int sl = (kk << 2) + (lane >> 4);
#pragma unroll
            for (int m = 0; m < 4; ++m) {
                int row = (wr << 6) + (m << 4) + (lane & 15);
                af[m][kk] = *reinterpret_cast<const bf16x8*>(&sA[(row << 7) + ((sl ^ (row & 7)) << 4)]);
            }
#pragma unroll
            for (int n = 0; n < 4; ++n) {
                int row = (wc << 6) + (n << 4) + (lane & 15);
                bfr[n][kk] = *reinterpret_cast<const bf16x8*>(&sB[(row << 7) + ((sl ^ (row & 7)) << 4)]);
            }
        }
#pragma unroll
        for (int kk = 0; kk < 2; ++kk)
#pragma unroll
            for (int m = 0; m < 4; ++m)
#pragma unroll
                for (int n = 0; n < 4; ++n)
                    acc[m][n] = __builtin_amdgcn_mfma_f32_16x16x32_bf16(af[m][kk], bfr[n][kk], acc[m][n], 0, 0, 0);
    }

    float* Cf = (float*)Cvp;
    __bf16* Ch = (__bf16*)Cvp;
#pragma unroll
    for (int m = 0; m < 4; ++m) {
        int grow0 = tm + (wr << 6) + (m << 4) + ((lane >> 4) << 2);
#pragma unroll
        for (int n = 0; n < 4; ++n) {
            int gcol = tn + (wc << 6) + (n << 4) + (lane & 15);
            if (gcol < N) {
#pragma unroll
                for (int j = 0; j < 4; ++j) {
                    int grow = grow0 + j;
                    if (grow < M) {
                        size_t o = (size_t)grow * ldc + gcol;
                        float v = acc[m][n][j];
                        if (cmode == 1)      Cf[o] = v + Cf[o];
                        else if (cmode == 2) Ch[o] = (__bf16)v;
                        else                 Cf[o] = v;
                    }
                }
            }
        }
    }
}

// ---------------- im2col for patch embed: xcol[9216][768] bf16 --------------
__global__ __launch_bounds__(256)
void k_im2col(const float* __restrict__ x, __bf16* __restrict__ xcol)
{
    int id = blockIdx.x * 256 + threadIdx.x;    // (row, ci, kh), 9216*48
    int kh = id & 15;
    int ci = (id >> 4) % 3;
    int row = id / 48;
    int b = row / 576, p = row % 576;
    int py = p / 24, px = p % 24;
    const float* src = x + ((size_t)(b*3 + ci)*384 + py*16 + kh)*384 + px*16;
    __bf16* dst = xcol + (size_t)row*768 + ci*256 + kh*16;
#pragma unroll
    for (int j = 0; j < 4; ++j) {
        float4 v = *reinterpret_cast<const float4*>(src + j*4);
        *reinterpret_cast<bf16x4*>(dst + j*4) = to_bf4(v.x, v.y, v.z, v.w);
    }
}

// --------- assemble tokens: cls+pos / patch+bias+pos -> h_tok (fp32) ---------
__global__ __launch_bounds__(256)
void k_assemble(const float* __restrict__ Ctmp, const float* __restrict__ pb,
                const float* __restrict__ cls, const float* __restrict__ pos,
                float* __restrict__ h_tok)
{
    int i4 = blockIdx.x * 256 + threadIdx.x;    // f4 index, 16*577*64
    int c4 = i4 & 63;
    int tok = (i4 >> 6) % 577;
    int b = i4 / (577*64);
    float4 pv = *reinterpret_cast<const float4*>(pos + tok*256 + c4*4);
    float4 r;
    if (tok == 0) {
        float4 cv = *reinterpret_cast<const float4*>(cls + c4*4);
        r.x = cv.x + pv.x; r.y = cv.y + pv.y; r.z = cv.z + pv.z; r.w = cv.w + pv.w;
    } else {
        float4 t = *reinterpret_cast<const float4*>(Ctmp + (size_t)(b*576 + tok - 1)*256 + c4*4);
        float4 bb = *reinterpret_cast<const float4*>(pb + c4*4);
        r.x = t.x + bb.x + pv.x; r.y = t.y + bb.y + pv.y;
        r.z = t.z + bb.z + pv.z; r.w = t.w + bb.w + pv.w;
    }
    *reinterpret_cast<float4*>(h_tok + (size_t)i4*4) = r;
}

// ---------------- LayerNorm over 256 -> bf16, one wave per row --------------
__global__ __launch_bounds__(256)
void k_ln(const float* __restrict__ X, const float* __restrict__ w,
          const float* __restrict__ bb, __bf16* __restrict__ O)
{
    int lane = threadIdx.x & 63;
    int row = blockIdx.x * 4 + (threadIdx.x >> 6);
    const float4 v = *reinterpret_cast<const float4*>(X + (size_t)row*256 + lane*4);
    float s1 = v.x + v.y + v.z + v.w;
    float s2 = v.x*v.x + v.y*v.y + v.z*v.z + v.w*v.w;
#pragma unroll
    for (int o2 = 32; o2; o2 >>= 1) { s1 += __shfl_xor(s1, o2); s2 += __shfl_xor(s2, o2); }
    float mu = s1 * (1.f/256.f);
    float var = s2 * (1.f/256.f) - mu*mu;
    float rs = rsqrtf(var + 1e-5f);
    float4 wv = *reinterpret_cast<const float4*>(w + lane*4);
    float4 bv = *reinterpret_cast<const float4*>(bb + lane*4);
    *reinterpret_cast<bf16x4*>(O + (size_t)row*256 + lane*4) =
        to_bf4((v.x - mu)*rs*wv.x + bv.x, (v.y - mu)*rs*wv.y + bv.y,
               (v.z - mu)*rs*wv.z + bv.z, (v.w - mu)*rs*wv.w + bv.w);
}

// ------------- causal depthwise conv K=4 + SiLU: xz[:, :512] -> xi ----------
__global__ __launch_bounds__(256)
void k_conv(const __bf16* __restrict__ xz, const float* __restrict__ cw,
            const float* __restrict__ cb, __bf16* __restrict__ xi)
{
    int gw = blockIdx.x * 4 + (threadIdx.x >> 6);   // 16*8*73 waves
    int lane = threadIdx.x & 63;
    int tc = gw % 73;
    int eg = (gw / 73) & 7;
    int b  = gw / (73*8);
    int e = eg*64 + lane;
    float4 wv = *reinterpret_cast<const float4*>(cw + e*4);
    float bias = cb[e];
    int t0 = tc * 8;
    float xv[11];
#pragma unroll
    for (int j = 0; j < 11; ++j) {
        int t = t0 - 3 + j;
        xv[j] = (t >= 0 && t < 577) ? (float)xz[(size_t)(b*577 + t)*1024 + e] : 0.f;
    }
#pragma unroll
    for (int j = 0; j < 8; ++j) {
        int t = t0 + j;
        if (t < 577) {
            float a = wv.x*xv[j] + wv.y*xv[j+1] + wv.z*xv[j+2] + wv.w*xv[j+3] + bias;
            float sgm = 1.f / (1.f + __expf(-a));
            xi[(size_t)(b*577 + t)*512 + e] = (__bf16)(a * sgm);
        }
    }
}

// ---- dt_proj (K=16) + softplus; writes tri2c[b][tc][e][j] = {dt, dt*u} ------
// chunk-contiguous layout: ((b*37 + tc)*512 + e)*32 + j*2
__global__ __launch_bounds__(256)
void k_dtfuse(const float* __restrict__ dbl, const float* __restrict__ dtw,
              const float* __restrict__ dtb, const __bf16* __restrict__ xi,
              float* __restrict__ tri2)
{
    __shared__ float dtr[16][16];
    const int tid = threadIdx.x;
    const int b    = blockIdx.x / 74;
    const int rr   = blockIdx.x % 74;
    const int tc   = rr >> 1;
    const int e    = ((rr & 1) << 8) + tid;
    const int nj   = (tc == 36) ? 1 : 16;
    {   // stage dt-rank rows for this chunk
        int j = tid >> 4, r = tid & 15;
        if (j < nj)
            dtr[j][r] = dbl[((size_t)(b*577) + tc*16 + j)*144 + r];
    }
    __syncthreads();
    const float* wp = dtw + e*16;
    float4 w0 = *reinterpret_cast<const float4*>(wp);
    float4 w1 = *reinterpret_cast<const float4*>(wp + 4);
    float4 w2 = *reinterpret_cast<const float4*>(wp + 8);
    float4 w3 = *reinterpret_cast<const float4*>(wp + 12);
    float bias = dtb[e];
    float* outp = tri2 + ((size_t)(b*37 + tc)*512 + e)*32;
    for (int j = 0; j < nj; ++j) {
        const float* dr = dtr[j];
        float accv = bias;
        accv += w0.x*dr[0] + w0.y*dr[1] + w0.z*dr[2] + w0.w*dr[3];
        accv += w1.x*dr[4] + w1.y*dr[5] + w1.z*dr[6] + w1.w*dr[7];
        accv += w2.x*dr[8] + w2.y*dr[9] + w2.z*dr[10] + w2.w*dr[11];
        accv += w3.x*dr[12] + w3.y*dr[13] + w3.z*dr[14] + w3.w*dr[15];
        float sp = accv > 20.f ? accv : log1pf(__expf(accv));
        float u = (float)xi[((size_t)(b*577) + tc*16 + j)*512 + e];
        float2 o; o.x = sp; o.y = sp * u;
        *reinterpret_cast<float2*>(outp + j*2) = o;
    }
}

// ------------- selective scan: wave = (b, 2 channels), lane = state s -------
// ND=2 channels/wave shares B/C loads (L2 traffic /2). tri2 chunk = 256B
// uniform block (merged s_loads). y stored chunk-transposed (dense 64B lines):
// ych[((b*37+c)*512+d)*16 + tt]. u*D applied in k_gate.
__global__ __launch_bounds__(256, 4)
void k_scan(const float* __restrict__ tri2, const float* __restrict__ dbl,
            const float* __restrict__ A_log, float* __restrict__ ych)
{
    __shared__ float tp[4*16*65];    // per-wave private pads
    const int tid  = threadIdx.x;
    const int lane = tid & 63;
    const int wv   = tid >> 6;                                            // 0..3
    const int bb   = blockIdx.x >> 6;                                     // batch
    const int d0   = __builtin_amdgcn_readfirstlane(((blockIdx.x & 63) << 3) + (wv << 1));
    const float al0 = -__expf(A_log[(size_t)d0*64 + lane]) * 1.44269504f;
    const float al1 = -__expf(A_log[(size_t)(d0+1)*64 + lane]) * 1.44269504f;
    const float2* trp = reinterpret_cast<const float2*>(tri2)
                      + ((size_t)bb*NCH*512 + d0)*16;                     // uniform
    const float* Bb = dbl + (size_t)bb*577*144 + 16 + lane;
    float* yo = ych + ((size_t)bb*NCH*512 + d0)*16;
    float* tpw = tp + wv*(16*65);
    const int g = lane >> 4, tt = lane & 15;
    float h0 = 0.f, h1 = 0.f;

    for (int c = 0; c < 36; ++c) {
        const int t0 = c << 4;
        float p0[16], p1[16];
#pragma unroll
        for (int j = 0; j < 16; ++j) {
            float2 u0 = trp[(size_t)c*8192 + j];
            float2 u1 = trp[(size_t)c*8192 + 16 + j];
            float Bv = Bb[(size_t)(t0 + j)*144];
            float Cv = Bb[(size_t)(t0 + j)*144 + 64];
            h0 = __builtin_fmaf(fast_exp2(u0.x*al0), h0, u0.y*Bv);
            h1 = __builtin_fmaf(fast_exp2(u1.x*al1), h1, u1.y*Bv);
            p0[j] = h0 * Cv;
            p1[j] = h1 * Cv;
        }
        // channel 0 transpose-reduce (stride-65 pad: conflict-free)
#pragma unroll
        for (int j = 0; j < 16; ++j) tpw[j*65 + lane] = p0[j];
        float s0 = 0.f;
        {
            const float* rp = tpw + tt*65 + g*16;
#pragma unroll
            for (int k = 0; k < 16; ++k) s0 += rp[k];
        }
        s0 += __shfl_xor(s0, 16); s0 += __shfl_xor(s0, 32);
        if (lane < 16) yo[(size_t)c*8192 + tt] = s0;
        // channel 1
#pragma unroll
        for (int j = 0; j < 16; ++j) tpw[j*65 + lane] = p1[j];
        float s1 = 0.f;
        {
            const float* rp = tpw + tt*65 + g*16;
#pragma unroll
            for (int k = 0; k < 16; ++k) s1 += rp[k];
        }
        s1 += __shfl_xor(s1, 16); s1 += __shfl_xor(s1, 32);
        if (lane < 16) yo[(size_t)c*8192 + 16 + tt] = s1;
    }
    {   // tail t = 576 (chunk 36, j = 0)
        float2 u0 = trp[(size_t)36*8192];
        float2 u1 = trp[(size_t)36*8192 + 16];
        float Bv = Bb[(size_t)576*144];
        float Cv = Bb[(size_t)576*144 + 64];
        h0 = __builtin_fmaf(fast_exp2(u0.x*al0), h0, u0.y*Bv);
        h1 = __builtin_fmaf(fast_exp2(u1.x*al1), h1, u1.y*Bv);
        float q0 = h0 * Cv, q1 = h1 * Cv;
#pragma unroll
        for (int o2 = 32; o2; o2 >>= 1) { q0 += __shfl_xor(q0, o2); q1 += __shfl_xor(q1, o2); }
        if (lane == 0) {
            yo[(size_t)36*8192] = q0;
            yo[(size_t)36*8192 + 16] = q1;
        }
    }
}

// ------------- yb = (ych + u*D) * silu(z)  (bf16 out for out_proj) ----------
__global__ __launch_bounds__(256)
void k_gate(const float* __restrict__ ych, const __bf16* __restrict__ xz,
            const __bf16* __restrict__ xi, const float* __restrict__ Dp,
            __bf16* __restrict__ yb)
{
    int i4 = blockIdx.x * 256 + threadIdx.x;   // (row, d4): 9232*128
    int row = i4 >> 7;
    int c4 = i4 & 127;
    int b = row / 577, t = row % 577;
    int cc = t >> 4, tt = t & 15;
    int d = c4 << 2;
    const float* yp = ych + ((size_t)(b*NCH + cc)*512 + d)*16 + tt;
    float y0 = yp[0], y1 = yp[16], y2 = yp[32], y3 = yp[48];
    bf16x4 u4 = *reinterpret_cast<const bf16x4*>(xi + (size_t)row*512 + d);
    bf16x4 z4 = *reinterpret_cast<const bf16x4*>(xz + (size_t)row*1024 + 512 + d);
    float4 dv = *reinterpret_cast<const float4*>(Dp + d);
    float z0 = (float)z4[0], z1 = (float)z4[1], z2 = (float)z4[2], z3 = (float)z4[3];
    float g0 = z0 / (1.f + __expf(-z0)), g1 = z1 / (1.f + __expf(-z1));
    float g2 = z2 / (1.f + __expf(-z2)), g3 = z3 / (1.f + __expf(-z3));
    *reinterpret_cast<bf16x4*>(yb + (size_t)row*512 + d) =
        to_bf4((y0 + (float)u4[0]*dv.x) * g0, (y1 + (float)u4[1]*dv.y) * g1,
               (y2 + (float)u4[2]*dv.z) * g2, (y3 + (float)u4[3]*dv.w) * g3);
}

// ---------------- final LN (cls token) + head -------------------------------
__global__ __launch_bounds__(256)
void k_head(const float* __restrict__ h_tok, const float* __restrict__ fw,
            const float* __restrict__ fb, const float* __restrict__ hw,
            const float* __restrict__ hb, float* __restrict__ out)
{
    int b = blockIdx.x, tid = threadIdx.x;
    __shared__ float sv[256];
    __shared__ float sr[16];
    float v = h_tok[(size_t)b*577*256 + tid];
    float s1 = v, s2 = v*v;
#pragma unroll
    for (int o2 = 32; o2; o2 >>= 1) { s1 += __shfl_xor(s1, o2); s2 += __shfl_xor(s2, o2); }
    int wave = tid >> 6;
    if ((tid & 63) == 0) { sr[wave] = s1; sr[wave + 8] = s2; }
    __syncthreads();
    float t1 = sr[0] + sr[1] + sr[2] + sr[3];
    float t2 = sr[8] + sr[9] + sr[10] + sr[11];
    float mu = t1 * (1.f/256.f);
    float var = t2 * (1.f/256.f) - mu*mu;
    float rs = rsqrtf(var + 1e-5f);
    sv[tid] = (v - mu)*rs*fw[tid] + fb[tid];
    __syncthreads();
    if (tid < 10) {
        float acc = hb[tid];
        for (int d2 = 0; d2 < 256; ++d2) acc += sv[d2]*hw[tid*256 + d2];
        out[b*10 + tid] = acc;
    }
}

extern "C" void kernel_launch(void* const* d_in, const int* in_sizes, int n_in,
                              void* d_out, int out_size, void* d_ws, size_t ws_size,
                              hipStream_t stream)
{
    const float* x         = (const float*)d_in[0];
    const float* patch_w   = (const float*)d_in[1];
    const float* patch_b   = (const float*)d_in[2];
    const float* cls_tok   = (const float*)d_in[3];
    const float* pos_emb   = (const float*)d_in[4];
    const float* norm_w    = (const float*)d_in[5];
    const float* norm_b    = (const float*)d_in[6];
    const float* in_proj_w = (const float*)d_in[7];
    const float* conv_w    = (const float*)d_in[8];
    const float* conv_b    = (const float*)d_in[9];
    const float* x_proj_w  = (const float*)d_in[10];
    const float* dt_proj_w = (const float*)d_in[11];
    const float* dt_proj_b = (const float*)d_in[12];
    const float* A_log     = (const float*)d_in[13];
    const float* D_ssm     = (const float*)d_in[14];
    const float* out_proj_w= (const float*)d_in[15];
    const float* fnorm_w   = (const float*)d_in[16];
    const float* fnorm_b   = (const float*)d_in[17];
    const float* head_w    = (const float*)d_in[18];
    const float* head_b    = (const float*)d_in[19];
    float* out = (float*)d_out;

    char* ws = (char*)d_ws;
    size_t off = 0;
    auto carveB = [&](size_t bytes) -> char* {
        char* p = ws + off;
        off += (bytes + 255) & ~(size_t)255;
        return p;
    };
    float*  h_tok = (float*) carveB((size_t)NROWS*DM*4);          //  9.45 MB
    __bf16* xln   = (__bf16*)carveB((size_t)NROWS*DM*2);          //  4.73 MB
    __bf16* xz    = (__bf16*)carveB((size_t)NROWS*1024*2);        // 18.9 MB (alias: xcol bf16 14.2)
    __bf16* xi    = (__bf16*)carveB((size_t)NROWS*DI*2);          //  9.45 MB
    float*  dbl   = (float*) carveB((size_t)NROWS*144*4);         //  5.32 MB
    float*  tri2  = (float*) carveB((size_t)16*NCH*DI*32*4);      // 38.8 MB
    float*  ych   = (float*) carveB((size_t)16*NCH*DI*16*4);      // 19.4 MB (alias: Ctmp fp32 9.45)
    __bf16* yb    = (__bf16*)carveB((size_t)NROWS*DI*2);          //  9.45 MB
    __bf16* pwb   = (__bf16*)carveB((size_t)196608*2);
    __bf16* iwb   = (__bf16*)carveB((size_t)6*1024*DM*2);
    __bf16* xwb   = (__bf16*)carveB((size_t)6*144*DI*2);
    __bf16* owb   = (__bf16*)carveB((size_t)6*DM*DI*2);
    __bf16* xcol  = xz;
    float*  Ctmp  = ych;

    // ---- weight conversion (once per launch) ----
    k_cvt<<<192, 256, 0, stream>>>(patch_w, pwb, 196608/4);
    k_cvt<<<1024, 256, 0, stream>>>(in_proj_w, iwb, (6*1024*DM)/4);
    k_cvt<<<432, 256, 0, stream>>>(x_proj_w, xwb, (6*144*DI)/4);
    k_cvt<<<768, 256, 0, stream>>>(out_proj_w, owb, (6*DM*DI)/4);

    // ---- patch embed ----
    k_im2col<<<1728, 256, 0, stream>>>(x, xcol);
    {
        dim3 g(2, 72);
        k_gemm<<<g, 256, 0, stream>>>(xcol, 768, pwb, 768, Ctmp, 256, PROWS, 256, 768, 0);
    }
    k_assemble<<<2308, 256, 0, stream>>>(Ctmp, patch_b, cls_tok, pos_emb, h_tok);

    // ---- 6 mamba blocks ----
    for (int i = 0; i < 6; ++i) {
        k_ln<<<2308, 256, 0, stream>>>(h_tok, norm_w + i*DM, norm_b + i*DM, xln);
        {
            dim3 g(8, 73);
            k_gemm<<<g, 256, 0, stream>>>(xln, DM, iwb + (size_t)i*1024*DM, DM,
                                          xz, 1024, NROWS, 1024, DM, 2);
        }
        k_conv<<<2336, 256, 0, stream>>>(xz, conv_w + (size_t)i*DI*4, conv_b + i*DI, xi);
        {
            dim3 g(2, 73);
            k_gemm<<<g, 256, 0, stream>>>(xi, DI, xwb + (size_t)i*144*DI, DI,
                                          dbl, 144, NROWS, 144, DI, 0);
        }
        k_dtfuse<<<16*NCH*2, 256, 0, stream>>>(dbl, dt_proj_w + (size_t)i*DI*16, dt_proj_b + i*DI,
                                               xi, tri2);
        k_scan<<<1024, 256, 0, stream>>>(tri2, dbl, A_log + (size_t)i*DI*DS_, ych);
        k_gate<<<4616, 256, 0, stream>>>(ych, xz, xi, D_ssm + i*DI, yb);
        {
            dim3 g(2, 73);
            k_gemm<<<g, 256, 0, stream>>>(yb, DI, owb + (size_t)i*DM*DI, DI,
                                          h_tok, DM, NROWS, DM, DI, 1);
        }
    }
    k_head<<<16, 256, 0, stream>>>(h_tok, fnorm_w, fnorm_b, head_w, head_b, out);
}

// Round 10
// 1577.707 us; speedup vs baseline: 1.1957x; 1.0735x over previous
//
#include <hip/hip_runtime.h>
#include <hip/hip_bf16.h>
#include <cstdint>
#include <cstddef>

#define L_TOK 577
#define DM 256
#define DI 512
#define DS_ 64
#define NROWS (16*577)      // 9232
#define PROWS (16*576)      // 9216
#define NCH 37              // ceil(577/16) time chunks

typedef float f32x4v __attribute__((ext_vector_type(4)));
typedef __bf16 bf16x8 __attribute__((ext_vector_type(8)));
typedef __bf16 bf16x4 __attribute__((ext_vector_type(4)));

__device__ __forceinline__ float fast_exp2(float x) {
#if __has_builtin(__builtin_amdgcn_exp2f)
    return __builtin_amdgcn_exp2f(x);
#else
    return __expf(x * 0.6931471805599453f);
#endif
}

__device__ __forceinline__ bf16x4 to_bf4(float a, float b, float c, float d) {
    bf16x4 r; r[0]=(__bf16)a; r[1]=(__bf16)b; r[2]=(__bf16)c; r[3]=(__bf16)d; return r;
}

// ---------------- fp32 -> bf16 bulk convert, all 4 weight sets --------------
__global__ __launch_bounds__(256)
void k_cvtall(const float* __restrict__ s0, __bf16* __restrict__ d0, int n0,
              const float* __restrict__ s1, __bf16* __restrict__ d1, int n1,
              const float* __restrict__ s2, __bf16* __restrict__ d2, int n2,
              const float* __restrict__ s3, __bf16* __restrict__ d3, int n3)
{
    int total = n0 + n1 + n2 + n3;
    for (int i = blockIdx.x*256 + threadIdx.x; i < total; i += gridDim.x*256) {
        const float* s; __bf16* d; int k = i;
        if (k < n0) { s = s0; d = d0; }
        else if ((k -= n0) < n1) { s = s1; d = d1; }
        else if ((k -= n1) < n2) { s = s2; d = d2; }
        else { k -= n2; s = s3; d = d3; }
        float4 v = *reinterpret_cast<const float4*>(s + (size_t)k*4);
        *reinterpret_cast<bf16x4*>(d + (size_t)k*4) = to_bf4(v.x, v.y, v.z, v.w);
    }
}

// ---------------- GEMM 128x128: C = A[M,K] * B[N,K]^T -----------------------
// cmode: 0 = fp32 store, 1 = fp32 accumulate (+=), 2 = bf16 store
__global__ __launch_bounds__(256)
void k_gemm(const __bf16* __restrict__ A, int lda,
            const __bf16* __restrict__ B, int ldb,
            void* __restrict__ Cvp, int ldc,
            int M, int N, int K, int cmode)
{
    __shared__ char sA[128*128];
    __shared__ char sB[128*128];
    const int tid  = threadIdx.x;
    const int lane = tid & 63;
    const int wave = tid >> 6;
    const int wr = wave >> 1, wc = wave & 1;
    const int tm = blockIdx.y * 128, tn = blockIdx.x * 128;

    f32x4v acc[4][4];
#pragma unroll
    for (int m = 0; m < 4; ++m)
#pragma unroll
        for (int n = 0; n < 4; ++n) acc[m][n] = (f32x4v){0.f, 0.f, 0.f, 0.f};

    const int nk = K >> 6;
    for (int kt = 0; kt < nk; ++kt) {
        const int k0 = kt << 6;
        __syncthreads();
#pragma unroll
        for (int i = 0; i < 4; ++i) {
            int c = tid + (i << 8);
            int row = c >> 3, slot = c & 7;
            int gr = tm + row; gr = gr < M ? gr : M - 1;
            bf16x8 va = *reinterpret_cast<const bf16x8*>(A + (size_t)gr*lda + k0 + (slot<<3));
            *reinterpret_cast<bf16x8*>(&sA[(row << 7) + ((slot ^ (row & 7)) << 4)]) = va;
        }
#pragma unroll
        for (int i = 0; i < 4; ++i) {
            int c = tid + (i << 8);
            int row = c >> 3, slot = c & 7;
            int gr = tn + row; gr = gr < N ? gr : N - 1;
            bf16x8 vb = *reinterpret_cast<const bf16x8*>(B + (size_t)gr*ldb + k0 + (slot<<3));
            *reinterpret_cast<bf16x8*>(&sB[(row << 7) + ((slot ^ (row & 7)) << 4)]) = vb;
        }
        __syncthreads();

        bf16x8 af[4][2], bfr[4][2];
#pragma unroll
        for (int kk = 0; kk < 2; ++kk) {
            int sl = (kk << 2) + (lane >> 4);
#pragma unroll
            for (int m = 0; m < 4; ++m) {
                int row = (wr << 6) + (m << 4) + (lane & 15);
                af[m][kk] = *reinterpret_cast<const bf16x8*>(&sA[(row << 7) + ((sl ^ (row & 7)) << 4)]);
            }
#pragma unroll
            for (int n = 0; n < 4; ++n) {
                int row = (wc << 6) + (n << 4) + (lane & 15);
                bfr[n][kk] = *reinterpret_cast<const bf16x8*>(&sB[(row << 7) + ((sl ^ (row & 7)) << 4)]);
            }
        }
#pragma unroll
        for (int kk = 0; kk < 2; ++kk)
#pragma unroll
            for (int m = 0; m < 4; ++m)
#pragma unroll
                for (int n = 0; n < 4; ++n)
                    acc[m][n] = __builtin_amdgcn_mfma_f32_16x16x32_bf16(af[m][kk], bfr[n][kk], acc[m][n], 0, 0, 0);
    }

    float* Cf = (float*)Cvp;
    __bf16* Ch = (__bf16*)Cvp;
#pragma unroll
    for (int m = 0; m < 4; ++m) {
        int grow0 = tm + (wr << 6) + (m << 4) + ((lane >> 4) << 2);
#pragma unroll
        for (int n = 0; n < 4; ++n) {
            int gcol = tn + (wc << 6) + (n << 4) + (lane & 15);
            if (gcol < N) {
#pragma unroll
                for (int j = 0; j < 4; ++j) {
                    int grow = grow0 + j;
                    if (grow < M) {
                        size_t o = (size_t)grow * ldc + gcol;
                        float v = acc[m][n][j];
                        if (cmode == 1)      Cf[o] = v + Cf[o];
                        else if (cmode == 2) Ch[o] = (__bf16)v;
                        else                 Cf[o] = v;
                    }
                }
            }
        }
    }
}

// ---------------- GEMM 64x64 (for small-N shapes: more blocks) --------------
__global__ __launch_bounds__(256)
void k_gemm64(const __bf16* __restrict__ A, int lda,
              const __bf16* __restrict__ B, int ldb,
              void* __restrict__ Cvp, int ldc,
              int M, int N, int K, int cmode)
{
    __shared__ char sA[64*128];
    __shared__ char sB[64*128];
    const int tid  = threadIdx.x;
    const int lane = tid & 63;
    const int wave = tid >> 6;
    const int wr = wave >> 1, wc = wave & 1;
    const int tm = blockIdx.y * 64, tn = blockIdx.x * 64;

    f32x4v acc[2][2];
#pragma unroll
    for (int m = 0; m < 2; ++m)
#pragma unroll
        for (int n = 0; n < 2; ++n) acc[m][n] = (f32x4v){0.f, 0.f, 0.f, 0.f};

    const int nk = K >> 6;
    for (int kt = 0; kt < nk; ++kt) {
        const int k0 = kt << 6;
        __syncthreads();
#pragma unroll
        for (int i = 0; i < 2; ++i) {
            int c = tid + (i << 8);
            int row = c >> 3, slot = c & 7;
            int gr = tm + row; gr = gr < M ? gr : M - 1;
            bf16x8 va = *reinterpret_cast<const bf16x8*>(A + (size_t)gr*lda + k0 + (slot<<3));
            *reinterpret_cast<bf16x8*>(&sA[(row << 7) + ((slot ^ (row & 7)) << 4)]) = va;
        }
#pragma unroll
        for (int i = 0; i < 2; ++i) {
            int c = tid + (i << 8);
            int row = c >> 3, slot = c & 7;
            int gr = tn + row; gr = gr < N ? gr : N - 1;
            bf16x8 vb = *reinterpret_cast<const bf16x8*>(B + (size_t)gr*ldb + k0 + (slot<<3));
            *reinterpret_cast<bf16x8*>(&sB[(row << 7) + ((slot ^ (row & 7)) << 4)]) = vb;
        }
        __syncthreads();

        bf16x8 af[2][2], bfr[2][2];
#pragma unroll
        for (int kk = 0; kk < 2; ++kk) {
            int sl = (kk << 2) + (lane >> 4);
#pragma unroll
            for (int m = 0; m < 2; ++m) {
                int row = (wr << 5) + (m << 4) + (lane & 15);
                af[m][kk] = *reinterpret_cast<const bf16x8*>(&sA[(row << 7) + ((sl ^ (row & 7)) << 4)]);
            }
#pragma unroll
            for (int n = 0; n < 2; ++n) {
                int row = (wc << 5) + (n << 4) + (lane & 15);
                bfr[n][kk] = *reinterpret_cast<const bf16x8*>(&sB[(row << 7) + ((sl ^ (row & 7)) << 4)]);
            }
        }
#pragma unroll
        for (int kk = 0; kk < 2; ++kk)
#pragma unroll
            for (int m = 0; m < 2; ++m)
#pragma unroll
                for (int n = 0; n < 2; ++n)
                    acc[m][n] = __builtin_amdgcn_mfma_f32_16x16x32_bf16(af[m][kk], bfr[n][kk], acc[m][n], 0, 0, 0);
    }

    float* Cf = (float*)Cvp;
    __bf16* Ch = (__bf16*)Cvp;
#pragma unroll
    for (int m = 0; m < 2; ++m) {
        int grow0 = tm + (wr << 5) + (m << 4) + ((lane >> 4) << 2);
#pragma unroll
        for (int n = 0; n < 2; ++n) {
            int gcol = tn + (wc << 5) + (n << 4) + (lane & 15);
            if (gcol < N) {
#pragma unroll
                for (int j = 0; j < 4; ++j) {
                    int grow = grow0 + j;
                    if (grow < M) {
                        size_t o = (size_t)grow * ldc + gcol;
                        float v = acc[m][n][j];
                        if (cmode == 1)      Cf[o] = v + Cf[o];
                        else if (cmode == 2) Ch[o] = (__bf16)v;
                        else                 Cf[o] = v;
                    }
                }
            }
        }
    }
}

// ---------------- im2col for patch embed: xcol[9216][768] bf16 --------------
__global__ __launch_bounds__(256)
void k_im2col(const float* __restrict__ x, __bf16* __restrict__ xcol)
{
    int id = blockIdx.x * 256 + threadIdx.x;
    int kh = id & 15;
    int ci = (id >> 4) % 3;
    int row = id / 48;
    int b = row / 576, p = row % 576;
    int py = p / 24, px = p % 24;
    const float* src = x + ((size_t)(b*3 + ci)*384 + py*16 + kh)*384 + px*16;
    __bf16* dst = xcol + (size_t)row*768 + ci*256 + kh*16;
#pragma unroll
    for (int j = 0; j < 4; ++j) {
        float4 v = *reinterpret_cast<const float4*>(src + j*4);
        *reinterpret_cast<bf16x4*>(dst + j*4) = to_bf4(v.x, v.y, v.z, v.w);
    }
}

// --------- assemble tokens: cls+pos / patch+bias+pos -> h_tok (fp32) ---------
__global__ __launch_bounds__(256)
void k_assemble(const float* __restrict__ Ctmp, const float* __restrict__ pb,
                const float* __restrict__ cls, const float* __restrict__ pos,
                float* __restrict__ h_tok)
{
    int i4 = blockIdx.x * 256 + threadIdx.x;
    int c4 = i4 & 63;
    int tok = (i4 >> 6) % 577;
    int b = i4 / (577*64);
    float4 pv = *reinterpret_cast<const float4*>(pos + tok*256 + c4*4);
    float4 r;
    if (tok == 0) {
        float4 cv = *reinterpret_cast<const float4*>(cls + c4*4);
        r.x = cv.x + pv.x; r.y = cv.y + pv.y; r.z = cv.z + pv.z; r.w = cv.w + pv.w;
    } else {
        float4 t = *reinterpret_cast<const float4*>(Ctmp + (size_t)(b*576 + tok - 1)*256 + c4*4);
        float4 bb = *reinterpret_cast<const float4*>(pb + c4*4);
        r.x = t.x + bb.x + pv.x; r.y = t.y + bb.y + pv.y;
        r.z = t.z + bb.z + pv.z; r.w = t.w + bb.w + pv.w;
    }
    *reinterpret_cast<float4*>(h_tok + (size_t)i4*4) = r;
}

// ---------------- LayerNorm over 256 -> bf16, one wave per row --------------
__global__ __launch_bounds__(256)
void k_ln(const float* __restrict__ X, const float* __restrict__ w,
          const float* __restrict__ bb, __bf16* __restrict__ O)
{
    int lane = threadIdx.x & 63;
    int row = blockIdx.x * 4 + (threadIdx.x >> 6);
    const float4 v = *reinterpret_cast<const float4*>(X + (size_t)row*256 + lane*4);
    float s1 = v.x + v.y + v.z + v.w;
    float s2 = v.x*v.x + v.y*v.y + v.z*v.z + v.w*v.w;
#pragma unroll
    for (int o2 = 32; o2; o2 >>= 1) { s1 += __shfl_xor(s1, o2); s2 += __shfl_xor(s2, o2); }
    float mu = s1 * (1.f/256.f);
    float var = s2 * (1.f/256.f) - mu*mu;
    float rs = rsqrtf(var + 1e-5f);
    float4 wv = *reinterpret_cast<const float4*>(w + lane*4);
    float4 bv = *reinterpret_cast<const float4*>(bb + lane*4);
    *reinterpret_cast<bf16x4*>(O + (size_t)row*256 + lane*4) =
        to_bf4((v.x - mu)*rs*wv.x + bv.x, (v.y - mu)*rs*wv.y + bv.y,
               (v.z - mu)*rs*wv.z + bv.z, (v.w - mu)*rs*wv.w + bv.w);
}

// ------------- causal depthwise conv K=4 + SiLU: xz[:, :512] -> xi ----------
__global__ __launch_bounds__(256)
void k_conv(const __bf16* __restrict__ xz, const float* __restrict__ cw,
            const float* __restrict__ cb, __bf16* __restrict__ xi)
{
    int gw = blockIdx.x * 4 + (threadIdx.x >> 6);
    int lane = threadIdx.x & 63;
    int tc = gw % 73;
    int eg = (gw / 73) & 7;
    int b  = gw / (73*8);
    int e = eg*64 + lane;
    float4 wv = *reinterpret_cast<const float4*>(cw + e*4);
    float bias = cb[e];
    int t0 = tc * 8;
    float xv[11];
#pragma unroll
    for (int j = 0; j < 11; ++j) {
        int t = t0 - 3 + j;
        xv[j] = (t >= 0 && t < 577) ? (float)xz[(size_t)(b*577 + t)*1024 + e] : 0.f;
    }
#pragma unroll
    for (int j = 0; j < 8; ++j) {
        int t = t0 + j;
        if (t < 577) {
            float a = wv.x*xv[j] + wv.y*xv[j+1] + wv.z*xv[j+2] + wv.w*xv[j+3] + bias;
            float sgm = 1.f / (1.f + __expf(-a));
            xi[(size_t)(b*577 + t)*512 + e] = (__bf16)(a * sgm);
        }
    }
}

// ---- dt_proj (K=16) + softplus; writes tri2c[b][tc][e][j] = {dt, dt*u} ------
__global__ __launch_bounds__(256)
void k_dtfuse(const __bf16* __restrict__ dbl, const float* __restrict__ dtw,
              const float* __restrict__ dtb, const __bf16* __restrict__ xi,
              float* __restrict__ tri2)
{
    __shared__ float dtr[16][16];
    const int tid = threadIdx.x;
    const int b    = blockIdx.x / 74;
    const int rr   = blockIdx.x % 74;
    const int tc   = rr >> 1;
    const int e    = ((rr & 1) << 8) + tid;
    const int nj   = (tc == 36) ? 1 : 16;
    {
        int j = tid >> 4, r = tid & 15;
        if (j < nj)
            dtr[j][r] = (float)dbl[((size_t)(b*577) + tc*16 + j)*144 + r];
    }
    __syncthreads();
    const float* wp = dtw + e*16;
    float4 w0 = *reinterpret_cast<const float4*>(wp);
    float4 w1 = *reinterpret_cast<const float4*>(wp + 4);
    float4 w2 = *reinterpret_cast<const float4*>(wp + 8);
    float4 w3 = *reinterpret_cast<const float4*>(wp + 12);
    float bias = dtb[e];
    float* outp = tri2 + ((size_t)(b*37 + tc)*512 + e)*32;
    for (int j = 0; j < nj; ++j) {
        const float* dr = dtr[j];
        float accv = bias;
        accv += w0.x*dr[0] + w0.y*dr[1] + w0.z*dr[2] + w0.w*dr[3];
        accv += w1.x*dr[4] + w1.y*dr[5] + w1.z*dr[6] + w1.w*dr[7];
        accv += w2.x*dr[8] + w2.y*dr[9] + w2.z*dr[10] + w2.w*dr[11];
        accv += w3.x*dr[12] + w3.y*dr[13] + w3.z*dr[14] + w3.w*dr[15];
        float sp = accv > 20.f ? accv : log1pf(__expf(accv));
        float u = (float)xi[((size_t)(b*577) + tc*16 + j)*512 + e];
        float2 o; o.x = sp; o.y = sp * u;
        *reinterpret_cast<float2*>(outp + j*2) = o;
    }
}

// ------------- selective scan: wave = (b, 2 channels), lane = state s -------
// Software-pipelined: B/C (bf16) prefetched one chunk ahead into regs;
// h*C written straight to per-wave LDS pads (stride-65, conflict-free);
// tri2 chunk = 256B uniform block (merged s_loads). u*D applied in k_gate.
#define LOADBC(c, Ba, Ca) do { \
    _Pragma("unroll") \
    for (int j_ = 0; j_ < 16; ++j_) { \
        Ba[j_] = (float)Bb[(size_t)((c)*16 + j_)*144]; \
        Ca[j_] = (float)Bb[(size_t)((c)*16 + j_)*144 + 64]; \
    } } while (0)

#define PROCC(c, Ba, Ca) do { \
    const float2* tc_ = trp + (size_t)(c)*8192; \
    _Pragma("unroll") \
    for (int j_ = 0; j_ < 16; ++j_) { \
        float2 u0 = tc_[j_]; \
        float2 u1 = tc_[16 + j_]; \
        h0 = __builtin_fmaf(fast_exp2(u0.x*al0), h0, u0.y*Ba[j_]); \
        h1 = __builtin_fmaf(fast_exp2(u1.x*al1), h1, u1.y*Ba[j_]); \
        tpwA[j_*65 + lane] = h0 * Ca[j_]; \
        tpwB[j_*65 + lane] = h1 * Ca[j_]; \
    } \
    float s0 = 0.f, s1 = 0.f; \
    { const float* rpA = tpwA + tt*65 + g*16; \
      const float* rpB = tpwB + tt*65 + g*16; \
      _Pragma("unroll") \
      for (int k_ = 0; k_ < 16; ++k_) { s0 += rpA[k_]; s1 += rpB[k_]; } } \
    s0 += __shfl_xor(s0, 16); s0 += __shfl_xor(s0, 32); \
    s1 += __shfl_xor(s1, 16); s1 += __shfl_xor(s1, 32); \
    if (lane < 16) { \
        yo[(size_t)(c)*8192 + tt] = s0; \
        yo[(size_t)(c)*8192 + 16 + tt] = s1; \
    } } while (0)

__global__ __launch_bounds__(256, 4)
void k_scan(const float* __restrict__ tri2, const __bf16* __restrict__ dbl,
            const float* __restrict__ A_log, float* __restrict__ ych)
{
    __shared__ float tp[8*16*65];    // 33.3 KB: 2 pads per wave
    const int tid  = threadIdx.x;
    const int lane = tid & 63;
    const int wv   = tid >> 6;
    const int bb   = blockIdx.x >> 6;
    const int d0   = __builtin_amdgcn_readfirstlane(((blockIdx.x & 63) << 3) + (wv << 1));
    const float al0 = -__expf(A_log[(size_t)d0*64 + lane]) * 1.44269504f;
    const float al1 = -__expf(A_log[(size_t)(d0+1)*64 + lane]) * 1.44269504f;
    const float2* trp = reinterpret_cast<const float2*>(tri2)
                      + ((size_t)bb*NCH*512 + d0)*16;
    const __bf16* Bb = dbl + (size_t)bb*577*144 + 16 + lane;
    float* yo = ych + ((size_t)bb*NCH*512 + d0)*16;
    float* tpwA = tp + (wv*2)*(16*65);
    float* tpwB = tp + (wv*2 + 1)*(16*65);
    const int g = lane >> 4, tt = lane & 15;
    float h0 = 0.f, h1 = 0.f;
    float B0[16], C0[16], B1[16], C1[16];

    LOADBC(0, B0, C0);
    for (int cc = 0; cc < 18; ++cc) {
        const int c0 = cc << 1;
        LOADBC(c0 + 1, B1, C1);
        PROCC(c0, B0, C0);
        if (cc < 17) LOADBC(c0 + 2, B0, C0);
        PROCC(c0 + 1, B1, C1);
    }
    {   // tail t = 576 (chunk 36, j = 0)
        float2 u0 = trp[(size_t)36*8192];
        float2 u1 = trp[(size_t)36*8192 + 16];
        float Bv = (float)Bb[(size_t)576*144];
        float Cv = (float)Bb[(size_t)576*144 + 64];
        h0 = __builtin_fmaf(fast_exp2(u0.x*al0), h0, u0.y*Bv);
        h1 = __builtin_fmaf(fast_exp2(u1.x*al1), h1, u1.y*Bv);
        float q0 = h0 * Cv, q1 = h1 * Cv;
#pragma unroll
        for (int o2 = 32; o2; o2 >>= 1) { q0 += __shfl_xor(q0, o2); q1 += __shfl_xor(q1, o2); }
        if (lane == 0) {
            yo[(size_t)36*8192] = q0;
            yo[(size_t)36*8192 + 16] = q1;
        }
    }
}

// ------------- yb = (ych + u*D) * silu(z)  (bf16 out for out_proj) ----------
__global__ __launch_bounds__(256)
void k_gate(const float* __restrict__ ych, const __bf16* __restrict__ xz,
            const __bf16* __restrict__ xi, const float* __restrict__ Dp,
            __bf16* __restrict__ yb)
{
    int i4 = blockIdx.x * 256 + threadIdx.x;   // (row, d4): 9232*128
    int row = i4 >> 7;
    int c4 = i4 & 127;
    int b = row / 577, t = row % 577;
    int cc = t >> 4, tt = t & 15;
    int d = c4 << 2;
    const float* yp = ych + ((size_t)(b*NCH + cc)*512 + d)*16 + tt;
    float y0 = yp[0], y1 = yp[16], y2 = yp[32], y3 = yp[48];
    bf16x4 u4 = *reinterpret_cast<const bf16x4*>(xi + (size_t)row*512 + d);
    bf16x4 z4 = *reinterpret_cast<const bf16x4*>(xz + (size_t)row*1024 + 512 + d);
    float4 dv = *reinterpret_cast<const float4*>(Dp + d);
    float z0 = (float)z4[0], z1 = (float)z4[1], z2 = (float)z4[2], z3 = (float)z4[3];
    float g0 = z0 / (1.f + __expf(-z0)), g1 = z1 / (1.f + __expf(-z1));
    float g2 = z2 / (1.f + __expf(-z2)), g3 = z3 / (1.f + __expf(-z3));
    *reinterpret_cast<bf16x4*>(yb + (size_t)row*512 + d) =
        to_bf4((y0 + (float)u4[0]*dv.x) * g0, (y1 + (float)u4[1]*dv.y) * g1,
               (y2 + (float)u4[2]*dv.z) * g2, (y3 + (float)u4[3]*dv.w) * g3);
}

// ---------------- final LN (cls token) + head -------------------------------
__global__ __launch_bounds__(256)
void k_head(const float* __restrict__ h_tok, const float* __restrict__ fw,
            const float* __restrict__ fb, const float* __restrict__ hw,
            const float* __restrict__ hb, float* __restrict__ out)
{
    int b = blockIdx.x, tid = threadIdx.x;
    __shared__ float sv[256];
    __shared__ float sr[16];
    float v = h_tok[(size_t)b*577*256 + tid];
    float s1 = v, s2 = v*v;
#pragma unroll
    for (int o2 = 32; o2; o2 >>= 1) { s1 += __shfl_xor(s1, o2); s2 += __shfl_xor(s2, o2); }
    int wave = tid >> 6;
    if ((tid & 63) == 0) { sr[wave] = s1; sr[wave + 8] = s2; }
    __syncthreads();
    float t1 = sr[0] + sr[1] + sr[2] + sr[3];
    float t2 = sr[8] + sr[9] + sr[10] + sr[11];
    float mu = t1 * (1.f/256.f);
    float var = t2 * (1.f/256.f) - mu*mu;
    float rs = rsqrtf(var + 1e-5f);
    sv[tid] = (v - mu)*rs*fw[tid] + fb[tid];
    __syncthreads();
    if (tid < 10) {
        float acc = hb[tid];
        for (int d2 = 0; d2 < 256; ++d2) acc += sv[d2]*hw[tid*256 + d2];
        out[b*10 + tid] = acc;
    }
}

extern "C" void kernel_launch(void* const* d_in, const int* in_sizes, int n_in,
                              void* d_out, int out_size, void* d_ws, size_t ws_size,
                              hipStream_t stream)
{
    const float* x         = (const float*)d_in[0];
    const float* patch_w   = (const float*)d_in[1];
    const float* patch_b   = (const float*)d_in[2];
    const float* cls_tok   = (const float*)d_in[3];
    const float* pos_emb   = (const float*)d_in[4];
    const float* norm_w    = (const float*)d_in[5];
    const float* norm_b    = (const float*)d_in[6];
    const float* in_proj_w = (const float*)d_in[7];
    const float* conv_w    = (const float*)d_in[8];
    const float* conv_b    = (const float*)d_in[9];
    const float* x_proj_w  = (const float*)d_in[10];
    const float* dt_proj_w = (const float*)d_in[11];
    const float* dt_proj_b = (const float*)d_in[12];
    const float* A_log     = (const float*)d_in[13];
    const float* D_ssm     = (const float*)d_in[14];
    const float* out_proj_w= (const float*)d_in[15];
    const float* fnorm_w   = (const float*)d_in[16];
    const float* fnorm_b   = (const float*)d_in[17];
    const float* head_w    = (const float*)d_in[18];
    const float* head_b    = (const float*)d_in[19];
    float* out = (float*)d_out;

    char* ws = (char*)d_ws;
    size_t off = 0;
    auto carveB = [&](size_t bytes) -> char* {
        char* p = ws + off;
        off += (bytes + 255) & ~(size_t)255;
        return p;
    };
    float*  h_tok = (float*) carveB((size_t)NROWS*DM*4);          //  9.45 MB
    __bf16* xln   = (__bf16*)carveB((size_t)NROWS*DM*2);          //  4.73 MB
    __bf16* xz    = (__bf16*)carveB((size_t)NROWS*1024*2);        // 18.9 MB (alias: xcol)
    __bf16* xi    = (__bf16*)carveB((size_t)NROWS*DI*2);          //  9.45 MB
    __bf16* dbl   = (__bf16*)carveB((size_t)NROWS*144*2);         //  2.66 MB
    float*  tri2  = (float*) carveB((size_t)16*NCH*DI*32*4);      // 38.8 MB
    float*  ych   = (float*) carveB((size_t)16*NCH*DI*16*4);      // 19.4 MB (alias: Ctmp)
    __bf16* yb    = (__bf16*)carveB((size_t)NROWS*DI*2);          //  9.45 MB
    __bf16* pwb   = (__bf16*)carveB((size_t)196608*2);
    __bf16* iwb   = (__bf16*)carveB((size_t)6*1024*DM*2);
    __bf16* xwb   = (__bf16*)carveB((size_t)6*144*DI*2);
    __bf16* owb   = (__bf16*)carveB((size_t)6*DM*DI*2);
    __bf16* xcol  = xz;
    float*  Ctmp  = ych;

    // ---- weight conversion (one launch) ----
    k_cvtall<<<2048, 256, 0, stream>>>(patch_w, pwb, 196608/4,
                                       in_proj_w, iwb, (6*1024*DM)/4,
                                       x_proj_w, xwb, (6*144*DI)/4,
                                       out_proj_w, owb, (6*DM*DI)/4);

    // ---- patch embed ----
    k_im2col<<<1728, 256, 0, stream>>>(x, xcol);
    {
        dim3 g(4, 144);
        k_gemm64<<<g, 256, 0, stream>>>(xcol, 768, pwb, 768, Ctmp, 256, PROWS, 256, 768, 0);
    }
    k_assemble<<<2308, 256, 0, stream>>>(Ctmp, patch_b, cls_tok, pos_emb, h_tok);

    // ---- 6 mamba blocks ----
    for (int i = 0; i < 6; ++i) {
        k_ln<<<2308, 256, 0, stream>>>(h_tok, norm_w + i*DM, norm_b + i*DM, xln);
        {
            dim3 g(8, 73);
            k_gemm<<<g, 256, 0, stream>>>(xln, DM, iwb + (size_t)i*1024*DM, DM,
                                          xz, 1024, NROWS, 1024, DM, 2);
        }
        k_conv<<<2336, 256, 0, stream>>>(xz, conv_w + (size_t)i*DI*4, conv_b + i*DI, xi);
        {
            dim3 g(3, 145);
            k_gemm64<<<g, 256, 0, stream>>>(xi, DI, xwb + (size_t)i*144*DI, DI,
                                            dbl, 144, NROWS, 144, DI, 2);
        }
        k_dtfuse<<<16*NCH*2, 256, 0, stream>>>(dbl, dt_proj_w + (size_t)i*DI*16, dt_proj_b + i*DI,
                                               xi, tri2);
        k_scan<<<1024, 256, 0, stream>>>(tri2, dbl, A_log + (size_t)i*DI*DS_, ych);
        k_gate<<<4616, 256, 0, stream>>>(ych, xz, xi, D_ssm + i*DI, yb);
        {
            dim3 g(4, 145);
            k_gemm64<<<g, 256, 0, stream>>>(yb, DI, owb + (size_t)i*DM*DI, DI,
                                            h_tok, DM, NROWS, DM, DI, 1);
        }
    }
    k_head<<<16, 256, 0, stream>>>(h_tok, fnorm_w, fnorm_b, head_w, head_b, out);
}

// Round 11
// 1528.157 us; speedup vs baseline: 1.2344x; 1.0324x over previous
//
#include <hip/hip_runtime.h>
#include <hip/hip_bf16.h>
#include <cstdint>
#include <cstddef>

#define L_TOK 577
#define DM 256
#define DI 512
#define DS_ 64
#define NROWS (16*577)      // 9232
#define PROWS (16*576)      // 9216
#define NCH 37              // ceil(577/16) time chunks

typedef float f32x4v __attribute__((ext_vector_type(4)));
typedef __bf16 bf16x8 __attribute__((ext_vector_type(8)));
typedef __bf16 bf16x4 __attribute__((ext_vector_type(4)));

__device__ __forceinline__ float fast_exp2(float x) {
#if __has_builtin(__builtin_amdgcn_exp2f)
    return __builtin_amdgcn_exp2f(x);
#else
    return __expf(x * 0.6931471805599453f);
#endif
}

__device__ __forceinline__ bf16x4 to_bf4(float a, float b, float c, float d) {
    bf16x4 r; r[0]=(__bf16)a; r[1]=(__bf16)b; r[2]=(__bf16)c; r[3]=(__bf16)d; return r;
}

// ---------------- fp32 -> bf16 bulk convert, all 4 weight sets --------------
__global__ __launch_bounds__(256)
void k_cvtall(const float* __restrict__ s0, __bf16* __restrict__ d0, int n0,
              const float* __restrict__ s1, __bf16* __restrict__ d1, int n1,
              const float* __restrict__ s2, __bf16* __restrict__ d2, int n2,
              const float* __restrict__ s3, __bf16* __restrict__ d3, int n3)
{
    int total = n0 + n1 + n2 + n3;
    for (int i = blockIdx.x*256 + threadIdx.x; i < total; i += gridDim.x*256) {
        const float* s; __bf16* d; int k = i;
        if (k < n0) { s = s0; d = d0; }
        else if ((k -= n0) < n1) { s = s1; d = d1; }
        else if ((k -= n1) < n2) { s = s2; d = d2; }
        else { k -= n2; s = s3; d = d3; }
        float4 v = *reinterpret_cast<const float4*>(s + (size_t)k*4);
        *reinterpret_cast<bf16x4*>(d + (size_t)k*4) = to_bf4(v.x, v.y, v.z, v.w);
    }
}

// ---------------- GEMM 128x128: C = A[M,K] * B[N,K]^T -----------------------
// cmode: 0 = fp32 store, 1 = fp32 accumulate (+=), 2 = bf16 store
__global__ __launch_bounds__(256)
void k_gemm(const __bf16* __restrict__ A, int lda,
            const __bf16* __restrict__ B, int ldb,
            void* __restrict__ Cvp, int ldc,
            int M, int N, int K, int cmode)
{
    __shared__ char sA[128*128];
    __shared__ char sB[128*128];
    const int tid  = threadIdx.x;
    const int lane = tid & 63;
    const int wave = tid >> 6;
    const int wr = wave >> 1, wc = wave & 1;
    const int tm = blockIdx.y * 128, tn = blockIdx.x * 128;

    f32x4v acc[4][4];
#pragma unroll
    for (int m = 0; m < 4; ++m)
#pragma unroll
        for (int n = 0; n < 4; ++n) acc[m][n] = (f32x4v){0.f, 0.f, 0.f, 0.f};

    const int nk = K >> 6;
    for (int kt = 0; kt < nk; ++kt) {
        const int k0 = kt << 6;
        __syncthreads();
#pragma unroll
        for (int i = 0; i < 4; ++i) {
            int c = tid + (i << 8);
            int row = c >> 3, slot = c & 7;
            int gr = tm + row; gr = gr < M ? gr : M - 1;
            bf16x8 va = *reinterpret_cast<const bf16x8*>(A + (size_t)gr*lda + k0 + (slot<<3));
            *reinterpret_cast<bf16x8*>(&sA[(row << 7) + ((slot ^ (row & 7)) << 4)]) = va;
        }
#pragma unroll
        for (int i = 0; i < 4; ++i) {
            int c = tid + (i << 8);
            int row = c >> 3, slot = c & 7;
            int gr = tn + row; gr = gr < N ? gr : N - 1;
            bf16x8 vb = *reinterpret_cast<const bf16x8*>(B + (size_t)gr*ldb + k0 + (slot<<3));
            *reinterpret_cast<bf16x8*>(&sB[(row << 7) + ((slot ^ (row & 7)) << 4)]) = vb;
        }
        __syncthreads();

        bf16x8 af[4][2], bfr[4][2];
#pragma unroll
        for (int kk = 0; kk < 2; ++kk) {
            int sl = (kk << 2) + (lane >> 4);
#pragma unroll
            for (int m = 0; m < 4; ++m) {
                int row = (wr << 6) + (m << 4) + (lane & 15);
                af[m][kk] = *reinterpret_cast<const bf16x8*>(&sA[(row << 7) + ((sl ^ (row & 7)) << 4)]);
            }
#pragma unroll
            for (int n = 0; n < 4; ++n) {
                int row = (wc << 6) + (n << 4) + (lane & 15);
                bfr[n][kk] = *reinterpret_cast<const bf16x8*>(&sB[(row << 7) + ((sl ^ (row & 7)) << 4)]);
            }
        }
#pragma unroll
        for (int kk = 0; kk < 2; ++kk)
#pragma unroll
            for (int m = 0; m < 4; ++m)
#pragma unroll
                for (int n = 0; n < 4; ++n)
                    acc[m][n] = __builtin_amdgcn_mfma_f32_16x16x32_bf16(af[m][kk], bfr[n][kk], acc[m][n], 0, 0, 0);
    }

    float* Cf = (float*)Cvp;
    __bf16* Ch = (__bf16*)Cvp;
#pragma unroll
    for (int m = 0; m < 4; ++m) {
        int grow0 = tm + (wr << 6) + (m << 4) + ((lane >> 4) << 2);
#pragma unroll
        for (int n = 0; n < 4; ++n) {
            int gcol = tn + (wc << 6) + (n << 4) + (lane & 15);
            if (gcol < N) {
#pragma unroll
                for (int j = 0; j < 4; ++j) {
                    int grow = grow0 + j;
                    if (grow < M) {
                        size_t o = (size_t)grow * ldc + gcol;
                        float v = acc[m][n][j];
                        if (cmode == 1)      Cf[o] = v + Cf[o];
                        else if (cmode == 2) Ch[o] = (__bf16)v;
                        else                 Cf[o] = v;
                    }
                }
            }
        }
    }
}

// ---------------- GEMM 64x64 (for small-N shapes: more blocks) --------------
__global__ __launch_bounds__(256)
void k_gemm64(const __bf16* __restrict__ A, int lda,
              const __bf16* __restrict__ B, int ldb,
              void* __restrict__ Cvp, int ldc,
              int M, int N, int K, int cmode)
{
    __shared__ char sA[64*128];
    __shared__ char sB[64*128];
    const int tid  = threadIdx.x;
    const int lane = tid & 63;
    const int wave = tid >> 6;
    const int wr = wave >> 1, wc = wave & 1;
    const int tm = blockIdx.y * 64, tn = blockIdx.x * 64;

    f32x4v acc[2][2];
#pragma unroll
    for (int m = 0; m < 2; ++m)
#pragma unroll
        for (int n = 0; n < 2; ++n) acc[m][n] = (f32x4v){0.f, 0.f, 0.f, 0.f};

    const int nk = K >> 6;
    for (int kt = 0; kt < nk; ++kt) {
        const int k0 = kt << 6;
        __syncthreads();
#pragma unroll
        for (int i = 0; i < 2; ++i) {
            int c = tid + (i << 8);
            int row = c >> 3, slot = c & 7;
            int gr = tm + row; gr = gr < M ? gr : M - 1;
            bf16x8 va = *reinterpret_cast<const bf16x8*>(A + (size_t)gr*lda + k0 + (slot<<3));
            *reinterpret_cast<bf16x8*>(&sA[(row << 7) + ((slot ^ (row & 7)) << 4)]) = va;
        }
#pragma unroll
        for (int i = 0; i < 2; ++i) {
            int c = tid + (i << 8);
            int row = c >> 3, slot = c & 7;
            int gr = tn + row; gr = gr < N ? gr : N - 1;
            bf16x8 vb = *reinterpret_cast<const bf16x8*>(B + (size_t)gr*ldb + k0 + (slot<<3));
            *reinterpret_cast<bf16x8*>(&sB[(row << 7) + ((slot ^ (row & 7)) << 4)]) = vb;
        }
        __syncthreads();

        bf16x8 af[2][2], bfr[2][2];
#pragma unroll
        for (int kk = 0; kk < 2; ++kk) {
            int sl = (kk << 2) + (lane >> 4);
#pragma unroll
            for (int m = 0; m < 2; ++m) {
                int row = (wr << 5) + (m << 4) + (lane & 15);
                af[m][kk] = *reinterpret_cast<const bf16x8*>(&sA[(row << 7) + ((sl ^ (row & 7)) << 4)]);
            }
#pragma unroll
            for (int n = 0; n < 2; ++n) {
                int row = (wc << 5) + (n << 4) + (lane & 15);
                bfr[n][kk] = *reinterpret_cast<const bf16x8*>(&sB[(row << 7) + ((sl ^ (row & 7)) << 4)]);
            }
        }
#pragma unroll
        for (int kk = 0; kk < 2; ++kk)
#pragma unroll
            for (int m = 0; m < 2; ++m)
#pragma unroll
                for (int n = 0; n < 2; ++n)
                    acc[m][n] = __builtin_amdgcn_mfma_f32_16x16x32_bf16(af[m][kk], bfr[n][kk], acc[m][n], 0, 0, 0);
    }

    float* Cf = (float*)Cvp;
    __bf16* Ch = (__bf16*)Cvp;
#pragma unroll
    for (int m = 0; m < 2; ++m) {
        int grow0 = tm + (wr << 5) + (m << 4) + ((lane >> 4) << 2);
#pragma unroll
        for (int n = 0; n < 2; ++n) {
            int gcol = tn + (wc << 5) + (n << 4) + (lane & 15);
            if (gcol < N) {
#pragma unroll
                for (int j = 0; j < 4; ++j) {
                    int grow = grow0 + j;
                    if (grow < M) {
                        size_t o = (size_t)grow * ldc + gcol;
                        float v = acc[m][n][j];
                        if (cmode == 1)      Cf[o] = v + Cf[o];
                        else if (cmode == 2) Ch[o] = (__bf16)v;
                        else                 Cf[o] = v;
                    }
                }
            }
        }
    }
}

// ---------------- im2col for patch embed: xcol[9216][768] bf16 --------------
__global__ __launch_bounds__(256)
void k_im2col(const float* __restrict__ x, __bf16* __restrict__ xcol)
{
    int id = blockIdx.x * 256 + threadIdx.x;
    int kh = id & 15;
    int ci = (id >> 4) % 3;
    int row = id / 48;
    int b = row / 576, p = row % 576;
    int py = p / 24, px = p % 24;
    const float* src = x + ((size_t)(b*3 + ci)*384 + py*16 + kh)*384 + px*16;
    __bf16* dst = xcol + (size_t)row*768 + ci*256 + kh*16;
#pragma unroll
    for (int j = 0; j < 4; ++j) {
        float4 v = *reinterpret_cast<const float4*>(src + j*4);
        *reinterpret_cast<bf16x4*>(dst + j*4) = to_bf4(v.x, v.y, v.z, v.w);
    }
}

// --------- assemble tokens: cls+pos / patch+bias+pos -> h_tok (fp32) ---------
__global__ __launch_bounds__(256)
void k_assemble(const float* __restrict__ Ctmp, const float* __restrict__ pb,
                const float* __restrict__ cls, const float* __restrict__ pos,
                float* __restrict__ h_tok)
{
    int i4 = blockIdx.x * 256 + threadIdx.x;
    int c4 = i4 & 63;
    int tok = (i4 >> 6) % 577;
    int b = i4 / (577*64);
    float4 pv = *reinterpret_cast<const float4*>(pos + tok*256 + c4*4);
    float4 r;
    if (tok == 0) {
        float4 cv = *reinterpret_cast<const float4*>(cls + c4*4);
        r.x = cv.x + pv.x; r.y = cv.y + pv.y; r.z = cv.z + pv.z; r.w = cv.w + pv.w;
    } else {
        float4 t = *reinterpret_cast<const float4*>(Ctmp + (size_t)(b*576 + tok - 1)*256 + c4*4);
        float4 bb = *reinterpret_cast<const float4*>(pb + c4*4);
        r.x = t.x + bb.x + pv.x; r.y = t.y + bb.y + pv.y;
        r.z = t.z + bb.z + pv.z; r.w = t.w + bb.w + pv.w;
    }
    *reinterpret_cast<float4*>(h_tok + (size_t)i4*4) = r;
}

// ---------------- LayerNorm over 256 -> bf16, one wave per row --------------
__global__ __launch_bounds__(256)
void k_ln(const float* __restrict__ X, const float* __restrict__ w,
          const float* __restrict__ bb, __bf16* __restrict__ O)
{
    int lane = threadIdx.x & 63;
    int row = blockIdx.x * 4 + (threadIdx.x >> 6);
    const float4 v = *reinterpret_cast<const float4*>(X + (size_t)row*256 + lane*4);
    float s1 = v.x + v.y + v.z + v.w;
    float s2 = v.x*v.x + v.y*v.y + v.z*v.z + v.w*v.w;
#pragma unroll
    for (int o2 = 32; o2; o2 >>= 1) { s1 += __shfl_xor(s1, o2); s2 += __shfl_xor(s2, o2); }
    float mu = s1 * (1.f/256.f);
    float var = s2 * (1.f/256.f) - mu*mu;
    float rs = rsqrtf(var + 1e-5f);
    float4 wv = *reinterpret_cast<const float4*>(w + lane*4);
    float4 bv = *reinterpret_cast<const float4*>(bb + lane*4);
    *reinterpret_cast<bf16x4*>(O + (size_t)row*256 + lane*4) =
        to_bf4((v.x - mu)*rs*wv.x + bv.x, (v.y - mu)*rs*wv.y + bv.y,
               (v.z - mu)*rs*wv.z + bv.z, (v.w - mu)*rs*wv.w + bv.w);
}

// ------------- causal depthwise conv K=4 + SiLU: xz[:, :512] -> xi ----------
__global__ __launch_bounds__(256)
void k_conv(const __bf16* __restrict__ xz, const float* __restrict__ cw,
            const float* __restrict__ cb, __bf16* __restrict__ xi)
{
    int gw = blockIdx.x * 4 + (threadIdx.x >> 6);
    int lane = threadIdx.x & 63;
    int tc = gw % 73;
    int eg = (gw / 73) & 7;
    int b  = gw / (73*8);
    int e = eg*64 + lane;
    float4 wv = *reinterpret_cast<const float4*>(cw + e*4);
    float bias = cb[e];
    int t0 = tc * 8;
    float xv[11];
#pragma unroll
    for (int j = 0; j < 11; ++j) {
        int t = t0 - 3 + j;
        xv[j] = (t >= 0 && t < 577) ? (float)xz[(size_t)(b*577 + t)*1024 + e] : 0.f;
    }
#pragma unroll
    for (int j = 0; j < 8; ++j) {
        int t = t0 + j;
        if (t < 577) {
            float a = wv.x*xv[j] + wv.y*xv[j+1] + wv.z*xv[j+2] + wv.w*xv[j+3] + bias;
            float sgm = 1.f / (1.f + __expf(-a));
            xi[(size_t)(b*577 + t)*512 + e] = (__bf16)(a * sgm);
        }
    }
}

// ---- dt_proj (K=16) + softplus; writes tri2c[b][tc][e][j] = {dt, dt*u} ------
__global__ __launch_bounds__(256)
void k_dtfuse(const __bf16* __restrict__ dbl, const float* __restrict__ dtw,
              const float* __restrict__ dtb, const __bf16* __restrict__ xi,
              float* __restrict__ tri2)
{
    __shared__ float dtr[16][16];
    const int tid = threadIdx.x;
    const int b    = blockIdx.x / 74;
    const int rr   = blockIdx.x % 74;
    const int tc   = rr >> 1;
    const int e    = ((rr & 1) << 8) + tid;
    const int nj   = (tc == 36) ? 1 : 16;
    {
        int j = tid >> 4, r = tid & 15;
        if (j < nj)
            dtr[j][r] = (float)dbl[((size_t)(b*577) + tc*16 + j)*144 + r];
    }
    __syncthreads();
    const float* wp = dtw + e*16;
    float4 w0 = *reinterpret_cast<const float4*>(wp);
    float4 w1 = *reinterpret_cast<const float4*>(wp + 4);
    float4 w2 = *reinterpret_cast<const float4*>(wp + 8);
    float4 w3 = *reinterpret_cast<const float4*>(wp + 12);
    float bias = dtb[e];
    float* outp = tri2 + ((size_t)(b*37 + tc)*512 + e)*32;
    for (int j = 0; j < nj; ++j) {
        const float* dr = dtr[j];
        float accv = bias;
        accv += w0.x*dr[0] + w0.y*dr[1] + w0.z*dr[2] + w0.w*dr[3];
        accv += w1.x*dr[4] + w1.y*dr[5] + w1.z*dr[6] + w1.w*dr[7];
        accv += w2.x*dr[8] + w2.y*dr[9] + w2.z*dr[10] + w2.w*dr[11];
        accv += w3.x*dr[12] + w3.y*dr[13] + w3.z*dr[14] + w3.w*dr[15];
        float sp = accv > 20.f ? accv : log1pf(__expf(accv));
        float u = (float)xi[((size_t)(b*577) + tc*16 + j)*512 + e];
        float2 o; o.x = sp; o.y = sp * u;
        *reinterpret_cast<float2*>(outp + j*2) = o;
    }
}

// ------------- selective scan: wave = (b, 2 channels), lane = state s -------
// Inline per-step bf16 B/C loads (compiler hoists the 16 independent loads of
// the unrolled chunk); h*C straight to per-wave LDS pads (stride-65,
// conflict-free); tri2 chunk = 256B uniform block (merged s_loads);
// y written chunk-transposed as bf16. u*D applied in k_gate.
__global__ __launch_bounds__(256, 4)
void k_scan(const float* __restrict__ tri2, const __bf16* __restrict__ dbl,
            const float* __restrict__ A_log, __bf16* __restrict__ ych)
{
    __shared__ float tp[8*16*65];    // 33.3 KB: 2 pads per wave
    const int tid  = threadIdx.x;
    const int lane = tid & 63;
    const int wv   = tid >> 6;
    const int bb   = blockIdx.x >> 6;
    const int d0   = __builtin_amdgcn_readfirstlane(((blockIdx.x & 63) << 3) + (wv << 1));
    const float al0 = -__expf(A_log[(size_t)d0*64 + lane]) * 1.44269504f;
    const float al1 = -__expf(A_log[(size_t)(d0+1)*64 + lane]) * 1.44269504f;
    const float2* trp = reinterpret_cast<const float2*>(tri2)
                      + ((size_t)bb*NCH*512 + d0)*16;
    const __bf16* Bb = dbl + (size_t)bb*577*144 + 16 + lane;
    __bf16* yo = ych + ((size_t)bb*NCH*512 + d0)*16;
    float* tpwA = tp + (wv*2)*(16*65);
    float* tpwB = tp + (wv*2 + 1)*(16*65);
    const int g = lane >> 4, tt = lane & 15;
    float h0 = 0.f, h1 = 0.f;

    for (int c = 0; c < 36; ++c) {
        const int t0 = c << 4;
        const float2* tcp = trp + (size_t)c*8192;
#pragma unroll
        for (int j = 0; j < 16; ++j) {
            float2 u0 = tcp[j];
            float2 u1 = tcp[16 + j];
            float Bv = (float)Bb[(size_t)(t0 + j)*144];
            float Cv = (float)Bb[(size_t)(t0 + j)*144 + 64];
            h0 = __builtin_fmaf(fast_exp2(u0.x*al0), h0, u0.y*Bv);
            h1 = __builtin_fmaf(fast_exp2(u1.x*al1), h1, u1.y*Bv);
            tpwA[j*65 + lane] = h0 * Cv;
            tpwB[j*65 + lane] = h1 * Cv;
        }
        float s0 = 0.f, s1 = 0.f;
        {
            const float* rpA = tpwA + tt*65 + g*16;
            const float* rpB = tpwB + tt*65 + g*16;
#pragma unroll
            for (int k = 0; k < 16; ++k) { s0 += rpA[k]; s1 += rpB[k]; }
        }
        s0 += __shfl_xor(s0, 16); s0 += __shfl_xor(s0, 32);
        s1 += __shfl_xor(s1, 16); s1 += __shfl_xor(s1, 32);
        if (lane < 16) {
            yo[(size_t)c*8192 + tt] = (__bf16)s0;
            yo[(size_t)c*8192 + 16 + tt] = (__bf16)s1;
        }
    }
    {   // tail t = 576 (chunk 36, j = 0)
        float2 u0 = trp[(size_t)36*8192];
        float2 u1 = trp[(size_t)36*8192 + 16];
        float Bv = (float)Bb[(size_t)576*144];
        float Cv = (float)Bb[(size_t)576*144 + 64];
        h0 = __builtin_fmaf(fast_exp2(u0.x*al0), h0, u0.y*Bv);
        h1 = __builtin_fmaf(fast_exp2(u1.x*al1), h1, u1.y*Bv);
        float q0 = h0 * Cv, q1 = h1 * Cv;
#pragma unroll
        for (int o2 = 32; o2; o2 >>= 1) { q0 += __shfl_xor(q0, o2); q1 += __shfl_xor(q1, o2); }
        if (lane == 0) {
            yo[(size_t)36*8192] = (__bf16)q0;
            yo[(size_t)36*8192 + 16] = (__bf16)q1;
        }
    }
}

// ------------- yb = (ych + u*D) * silu(z)  (bf16 out for out_proj) ----------
__global__ __launch_bounds__(256)
void k_gate(const __bf16* __restrict__ ych, const __bf16* __restrict__ xz,
            const __bf16* __restrict__ xi, const float* __restrict__ Dp,
            __bf16* __restrict__ yb)
{
    int i4 = blockIdx.x * 256 + threadIdx.x;   // (row, d4): 9232*128
    int row = i4 >> 7;
    int c4 = i4 & 127;
    int b = row / 577, t = row % 577;
    int cc = t >> 4, tt = t & 15;
    int d = c4 << 2;
    const __bf16* yp = ych + ((size_t)(b*NCH + cc)*512 + d)*16 + tt;
    float y0 = (float)yp[0], y1 = (float)yp[16], y2 = (float)yp[32], y3 = (float)yp[48];
    bf16x4 u4 = *reinterpret_cast<const bf16x4*>(xi + (size_t)row*512 + d);
    bf16x4 z4 = *reinterpret_cast<const bf16x4*>(xz + (size_t)row*1024 + 512 + d);
    float4 dv = *reinterpret_cast<const float4*>(Dp + d);
    float z0 = (float)z4[0], z1 = (float)z4[1], z2 = (float)z4[2], z3 = (float)z4[3];
    float g0 = z0 / (1.f + __expf(-z0)), g1 = z1 / (1.f + __expf(-z1));
    float g2 = z2 / (1.f + __expf(-z2)), g3 = z3 / (1.f + __expf(-z3));
    *reinterpret_cast<bf16x4*>(yb + (size_t)row*512 + d) =
        to_bf4((y0 + (float)u4[0]*dv.x) * g0, (y1 + (float)u4[1]*dv.y) * g1,
               (y2 + (float)u4[2]*dv.z) * g2, (y3 + (float)u4[3]*dv.w) * g3);
}

// ---------------- final LN (cls token) + head -------------------------------
__global__ __launch_bounds__(256)
void k_head(const float* __restrict__ h_tok, const float* __restrict__ fw,
            const float* __restrict__ fb, const float* __restrict__ hw,
            const float* __restrict__ hb, float* __restrict__ out)
{
    int b = blockIdx.x, tid = threadIdx.x;
    __shared__ float sv[256];
    __shared__ float sr[16];
    float v = h_tok[(size_t)b*577*256 + tid];
    float s1 = v, s2 = v*v;
#pragma unroll
    for (int o2 = 32; o2; o2 >>= 1) { s1 += __shfl_xor(s1, o2); s2 += __shfl_xor(s2, o2); }
    int wave = tid >> 6;
    if ((tid & 63) == 0) { sr[wave] = s1; sr[wave + 8] = s2; }
    __syncthreads();
    float t1 = sr[0] + sr[1] + sr[2] + sr[3];
    float t2 = sr[8] + sr[9] + sr[10] + sr[11];
    float mu = t1 * (1.f/256.f);
    float var = t2 * (1.f/256.f) - mu*mu;
    float rs = rsqrtf(var + 1e-5f);
    sv[tid] = (v - mu)*rs*fw[tid] + fb[tid];
    __syncthreads();
    if (tid < 10) {
        float acc = hb[tid];
        for (int d2 = 0; d2 < 256; ++d2) acc += sv[d2]*hw[tid*256 + d2];
        out[b*10 + tid] = acc;
    }
}

extern "C" void kernel_launch(void* const* d_in, const int* in_sizes, int n_in,
                              void* d_out, int out_size, void* d_ws, size_t ws_size,
                              hipStream_t stream)
{
    const float* x         = (const float*)d_in[0];
    const float* patch_w   = (const float*)d_in[1];
    const float* patch_b   = (const float*)d_in[2];
    const float* cls_tok   = (const float*)d_in[3];
    const float* pos_emb   = (const float*)d_in[4];
    const float* norm_w    = (const float*)d_in[5];
    const float* norm_b    = (const float*)d_in[6];
    const float* in_proj_w = (const float*)d_in[7];
    const float* conv_w    = (const float*)d_in[8];
    const float* conv_b    = (const float*)d_in[9];
    const float* x_proj_w  = (const float*)d_in[10];
    const float* dt_proj_w = (const float*)d_in[11];
    const float* dt_proj_b = (const float*)d_in[12];
    const float* A_log     = (const float*)d_in[13];
    const float* D_ssm     = (const float*)d_in[14];
    const float* out_proj_w= (const float*)d_in[15];
    const float* fnorm_w   = (const float*)d_in[16];
    const float* fnorm_b   = (const float*)d_in[17];
    const float* head_w    = (const float*)d_in[18];
    const float* head_b    = (const float*)d_in[19];
    float* out = (float*)d_out;

    char* ws = (char*)d_ws;
    size_t off = 0;
    auto carveB = [&](size_t bytes) -> char* {
        char* p = ws + off;
        off += (bytes + 255) & ~(size_t)255;
        return p;
    };
    float*  h_tok = (float*) carveB((size_t)NROWS*DM*4);          //  9.45 MB
    __bf16* xln   = (__bf16*)carveB((size_t)NROWS*DM*2);          //  4.73 MB
    __bf16* xz    = (__bf16*)carveB((size_t)NROWS*1024*2);        // 18.9 MB (alias: xcol)
    __bf16* xi    = (__bf16*)carveB((size_t)NROWS*DI*2);          //  9.45 MB
    __bf16* dbl   = (__bf16*)carveB((size_t)NROWS*144*2);         //  2.66 MB
    float*  tri2  = (float*) carveB((size_t)16*NCH*DI*32*4);      // 38.8 MB
    __bf16* ych   = (__bf16*)carveB((size_t)16*NCH*DI*16*2);      //  9.70 MB (alias: Ctmp fp32 9.44)
    __bf16* yb    = (__bf16*)carveB((size_t)NROWS*DI*2);          //  9.45 MB
    __bf16* pwb   = (__bf16*)carveB((size_t)196608*2);
    __bf16* iwb   = (__bf16*)carveB((size_t)6*1024*DM*2);
    __bf16* xwb   = (__bf16*)carveB((size_t)6*144*DI*2);
    __bf16* owb   = (__bf16*)carveB((size_t)6*DM*DI*2);
    __bf16* xcol  = xz;
    float*  Ctmp  = (float*)ych;

    // ---- weight conversion (one launch) ----
    k_cvtall<<<2048, 256, 0, stream>>>(patch_w, pwb, 196608/4,
                                       in_proj_w, iwb, (6*1024*DM)/4,
                                       x_proj_w, xwb, (6*144*DI)/4,
                                       out_proj_w, owb, (6*DM*DI)/4);

    // ---- patch embed ----
    k_im2col<<<1728, 256, 0, stream>>>(x, xcol);
    {
        dim3 g(4, 144);
        k_gemm64<<<g, 256, 0, stream>>>(xcol, 768, pwb, 768, Ctmp, 256, PROWS, 256, 768, 0);
    }
    k_assemble<<<2308, 256, 0, stream>>>(Ctmp, patch_b, cls_tok, pos_emb, h_tok);

    // ---- 6 mamba blocks ----
    for (int i = 0; i < 6; ++i) {
        k_ln<<<2308, 256, 0, stream>>>(h_tok, norm_w + i*DM, norm_b + i*DM, xln);
        {
            dim3 g(8, 73);
            k_gemm<<<g, 256, 0, stream>>>(xln, DM, iwb + (size_t)i*1024*DM, DM,
                                          xz, 1024, NROWS, 1024, DM, 2);
        }
        k_conv<<<2336, 256, 0, stream>>>(xz, conv_w + (size_t)i*DI*4, conv_b + i*DI, xi);
        {
            dim3 g(3, 145);
            k_gemm64<<<g, 256, 0, stream>>>(xi, DI, xwb + (size_t)i*144*DI, DI,
                                            dbl, 144, NROWS, 144, DI, 2);
        }
        k_dtfuse<<<16*NCH*2, 256, 0, stream>>>(dbl, dt_proj_w + (size_t)i*DI*16, dt_proj_b + i*DI,
                                               xi, tri2);
        k_scan<<<1024, 256, 0, stream>>>(tri2, dbl, A_log + (size_t)i*DI*DS_, ych);
        k_gate<<<4616, 256, 0, stream>>>(ych, xz, xi, D_ssm + i*DI, yb);
        {
            dim3 g(4, 145);
            k_gemm64<<<g, 256, 0, stream>>>(yb, DI, owb + (size_t)i*DM*DI, DI,
                                            h_tok, DM, NROWS, DM, DI, 1);
        }
    }
    k_head<<<16, 256, 0, stream>>>(h_tok, fnorm_w, fnorm_b, head_w, head_b, out);
}